// Round 5
// baseline (443.915 us; speedup 1.0000x reference)
//
#include <hip/hip_runtime.h>
#include <hip/hip_cooperative_groups.h>
#include <math.h>

namespace cg = cooperative_groups;

// B=8, N=32, M=64, D=128, OUT=128, K=3, P=N*N=1024, r=512
#define EPS 1e-5f

// stats layout (floats) in ws[0..1023]:
//  [0..127]   sum_sc   [128..255] sq_sc
//  [256..319] sum1     [320..383] sq1
//  [384..447] sum2     [448..511] sq2
//  [512..543] sum3     [544..575] sq3

__device__ __forceinline__ void fma4(float4& a, float s, const float4& v) {
    a.x += s * v.x; a.y += s * v.y; a.z += s * v.z; a.w += s * v.w;
}

// Shared-memory union across phases (max 50176 B).
union SharedU {
    struct { float s_x[64 * 128]; float s_wT[64 * 68]; } p1;          // 50176 B
    struct { float y_s[32 * 132]; float S_s[32]; unsigned int m_s[32]; } p2;
    struct { float lds[4 * 2304]; } p3;                                // 36864 B
    struct { float att_s[32 * 33]; float y_sh[32 * 128]; float redS[4], redQ[4]; } p5;
    struct { float z_s[66 * 130]; float a2_s[64], c2_s[64]; float redS[4], redQ[4]; } p6;
    struct { float z_s[64 * 128]; float s_wT[64 * 68]; } p7;           // 50176 B
};

// ---------------------------------------------------------------------------
// P1: t_sc[b,o,n,d] = sum_m W_sc[o,m] x[b,n,m,d]; t_l1 likewise for W_l1.
__device__ __forceinline__ void phase1(
    SharedU& su, const float* __restrict__ x, const float* __restrict__ Wsc,
    const float* __restrict__ Wl1, float* __restrict__ t_sc,
    float* __restrict__ t_l1, float* __restrict__ stats, int g, int bn, int t)
{
    float* s_x  = su.p1.s_x;
    float* s_wT = su.p1.s_wT;
    int b = bn >> 5, n = bn & 31;

    const float4* xg = (const float4*)(x + (size_t)bn * 8192);
    for (int i = t; i < 2048; i += 256) ((float4*)s_x)[i] = xg[i];

    const float* wbase = (g < 2) ? (Wsc + (size_t)g * 64 * 64) : Wl1;
    for (int i = t; i < 1024; i += 256) {
        int m = i >> 4, rq = (i & 15) * 4;
        float4 wv;
        wv.x = wbase[(size_t)(rq + 0) * 64 + m];
        wv.y = wbase[(size_t)(rq + 1) * 64 + m];
        wv.z = wbase[(size_t)(rq + 2) * 64 + m];
        wv.w = wbase[(size_t)(rq + 3) * 64 + m];
        *(float4*)(s_wT + m * 68 + rq) = wv;
    }
    __syncthreads();

    int wv = t >> 6, lane = t & 63;
    int dl = lane & 15;
    int g4 = lane >> 4;
    int d0 = dl * 8;
    int c0 = wv * 16 + g4 * 4;

    float4 acc[4][2];
#pragma unroll
    for (int i = 0; i < 4; i++) { acc[i][0] = make_float4(0,0,0,0); acc[i][1] = make_float4(0,0,0,0); }

    for (int m = 0; m < 64; m += 2) {
        float4 x00 = *(const float4*)(s_x + m * 128 + d0);
        float4 x01 = *(const float4*)(s_x + m * 128 + d0 + 4);
        float4 x10 = *(const float4*)(s_x + (m + 1) * 128 + d0);
        float4 x11 = *(const float4*)(s_x + (m + 1) * 128 + d0 + 4);
        float4 w0 = *(const float4*)(s_wT + m * 68 + c0);
        float4 w1 = *(const float4*)(s_wT + (m + 1) * 68 + c0);
        fma4(acc[0][0], w0.x, x00); fma4(acc[0][1], w0.x, x01);
        fma4(acc[1][0], w0.y, x00); fma4(acc[1][1], w0.y, x01);
        fma4(acc[2][0], w0.z, x00); fma4(acc[2][1], w0.z, x01);
        fma4(acc[3][0], w0.w, x00); fma4(acc[3][1], w0.w, x01);
        fma4(acc[0][0], w1.x, x10); fma4(acc[0][1], w1.x, x11);
        fma4(acc[1][0], w1.y, x10); fma4(acc[1][1], w1.y, x11);
        fma4(acc[2][0], w1.z, x10); fma4(acc[2][1], w1.z, x11);
        fma4(acc[3][0], w1.w, x10); fma4(acc[3][1], w1.w, x11);
    }

#pragma unroll
    for (int i = 0; i < 4; i++) {
        int cc = g * 64 + c0 + i;
        float4 v0 = acc[i][0], v1 = acc[i][1];
        float* dst;
        if (cc < 128) dst = t_sc + (((size_t)(b * 128 + cc)) * 32 + n) * 128 + d0;
        else          dst = t_l1 + (((size_t)(b * 64 + (cc - 128))) * 32 + n) * 128 + d0;
        *(float4*)dst = v0;
        *(float4*)(dst + 4) = v1;
        float s = v0.x + v0.y + v0.z + v0.w + v1.x + v1.y + v1.z + v1.w;
        float q = v0.x*v0.x + v0.y*v0.y + v0.z*v0.z + v0.w*v0.w
                + v1.x*v1.x + v1.y*v1.y + v1.z*v1.z + v1.w*v1.w;
#pragma unroll
        for (int off = 8; off > 0; off >>= 1) {
            s += __shfl_down(s, off, 16);
            q += __shfl_down(q, off, 16);
        }
        if (dl == 0) {
            if (cc < 128) {
                atomicAdd(&stats[cc], s);
                atomicAdd(&stats[cc + 128], q);
            } else {
                atomicAdd(&stats[256 + (cc - 128)], s);
                atomicAdd(&stats[320 + (cc - 128)], q);
            }
        }
    }
}

// ---------------------------------------------------------------------------
// P2: per (b,m): y = bn1(t_l1); row sums; dot/eq pairs; E; maskbits; store y.
__device__ __forceinline__ void phase2(
    SharedU& su, const float* __restrict__ t_l1, const float* __restrict__ g1,
    const float* __restrict__ b1, const float* __restrict__ stats,
    float* __restrict__ y_g, float* __restrict__ E,
    unsigned int* __restrict__ maskbits, int bm, int t)
{
    float* y_s = su.p2.y_s;
    float* S_s = su.p2.S_s;
    unsigned int* m_s = su.p2.m_s;
    int m = bm & 63;
    float mean = stats[256 + m] * (1.0f / 32768.0f);
    float var  = stats[320 + m] * (1.0f / 32768.0f) - mean * mean;
    float a = g1[m] * rsqrtf(var + EPS);
    float c = b1[m] - a * mean;

    if (t < 32) m_s[t] = 0u;
    const float4* src = (const float4*)(t_l1 + (size_t)bm * 4096);
    for (int i = t; i < 1024; i += 256) {
        float4 v = src[i];
        v.x = a * v.x + c; v.y = a * v.y + c; v.z = a * v.z + c; v.w = a * v.w + c;
        int row = i >> 5, col = (i & 31) * 4;
        *(float4*)(y_s + row * 132 + col) = v;
    }
    __syncthreads();

    {   // row sums
        int r = t >> 3, j = t & 7;
        float s = 0.f;
        const float* yr = y_s + r * 132 + j * 16;
#pragma unroll
        for (int dd = 0; dd < 16; dd++) s += yr[dd];
#pragma unroll
        for (int off = 4; off > 0; off >>= 1) s += __shfl_down(s, off, 8);
        if (j == 0) S_s[r] = s;
    }
    __syncthreads();

    int i = t >> 3, j0 = (t & 7) * 4;
    float dot[4] = {0.f, 0.f, 0.f, 0.f};
    float eqs[4] = {0.f, 0.f, 0.f, 0.f};
    const float* yi = y_s + i * 132;
    for (int dq = 0; dq < 32; dq++) {
        float4 a4 = *(const float4*)(yi + dq * 4);
#pragma unroll
        for (int q = 0; q < 4; q++) {
            float4 b4 = *(const float4*)(y_s + (j0 + q) * 132 + dq * 4);
            dot[q] += a4.x * b4.x + a4.y * b4.y + a4.z * b4.z + a4.w * b4.w;
            eqs[q] += (a4.x == b4.x ? b4.x : 0.f) + (a4.y == b4.y ? b4.y : 0.f)
                    + (a4.z == b4.z ? b4.z : 0.f) + (a4.w == b4.w ? b4.w : 0.f);
        }
    }
    float Si = S_s[i];
    unsigned int bits = 0u;
    float ev[4];
#pragma unroll
    for (int q = 0; q < 4; q++) {
        float Sj = S_s[j0 + q];
        float num = dot[q] - Si * Sj * (1.0f / 128.0f);
        if (num > 0.f) bits |= (1u << (j0 + q));
        ev[q] = (Si + 2.f * Sj - eqs[q]) * (1.0f / 256.0f);
    }
    atomicOr(&m_s[i], bits);
    *(float4*)(E + (size_t)bm * 1024 + i * 32 + j0) = make_float4(ev[0], ev[1], ev[2], ev[3]);
    __syncthreads();
    if (t < 32) maskbits[bm * 32 + t] = m_s[t];

    float4* yd = (float4*)(y_g + (size_t)bm * 4096);
    for (int idx = t; idx < 1024; idx += 256) {
        int row = idx >> 5, col = (idx & 31) * 4;
        yd[idx] = *(const float4*)(y_s + row * 132 + col);
    }
}

// ---------------------------------------------------------------------------
// P3/P4: C[r,c] = epi( sum_k A[r,k] * Bm[c,k] ). 32x32 tile, in-block wave
// split-K (4 waves, wave-private LDS slabs). MODE 0: relu, MODE 1: sigmoid.
template<int KDIM, int MODE>
__device__ __forceinline__ void gemm_phase(
    SharedU& su, const float* __restrict__ A, const float* __restrict__ Bm,
    float* __restrict__ C, int NC, int ct, int rt, int t)
{
    float* lds = su.p3.lds;
    int w = t >> 6, l = t & 63;
    int row0 = rt * 32, col0 = ct * 32;
    float* As = lds + w * 2304;
    float* Bs = As + 1152;
    int rg = l >> 3;
    int cg = l & 7;
    int kq = (l & 7) * 4;
    constexpr int SLABS = KDIM / 128;

    float4 acc[4];
#pragma unroll
    for (int ii = 0; ii < 4; ii++) acc[ii] = make_float4(0,0,0,0);

    float4 av[4], bv[4], av2[4], bv2[4];
    int k0 = w * 32;
#pragma unroll
    for (int rr = 0; rr < 4; rr++) {
        int r = rg + rr * 8;
        av[rr] = *(const float4*)(A  + (size_t)(row0 + r) * KDIM + k0 + kq);
        bv[rr] = *(const float4*)(Bm + (size_t)(col0 + r) * KDIM + k0 + kq);
    }

    for (int s = 0; s < SLABS; s++) {
#pragma unroll
        for (int rr = 0; rr < 4; rr++) {
            int r = rg + rr * 8;
            As[(kq + 0) * 36 + r] = av[rr].x; As[(kq + 1) * 36 + r] = av[rr].y;
            As[(kq + 2) * 36 + r] = av[rr].z; As[(kq + 3) * 36 + r] = av[rr].w;
            Bs[(kq + 0) * 36 + r] = bv[rr].x; Bs[(kq + 1) * 36 + r] = bv[rr].y;
            Bs[(kq + 2) * 36 + r] = bv[rr].z; Bs[(kq + 3) * 36 + r] = bv[rr].w;
        }
        if (s + 1 < SLABS) {
            int kn = (4 * (s + 1) + w) * 32;
#pragma unroll
            for (int rr = 0; rr < 4; rr++) {
                int r = rg + rr * 8;
                av2[rr] = *(const float4*)(A  + (size_t)(row0 + r) * KDIM + kn + kq);
                bv2[rr] = *(const float4*)(Bm + (size_t)(col0 + r) * KDIM + kn + kq);
            }
        }
#pragma unroll
        for (int k = 0; k < 32; k++) {
            float4 a = *(const float4*)(As + k * 36 + rg * 4);
            float4 b = *(const float4*)(Bs + k * 36 + cg * 4);
            fma4(acc[0], a.x, b);
            fma4(acc[1], a.y, b);
            fma4(acc[2], a.z, b);
            fma4(acc[3], a.w, b);
        }
#pragma unroll
        for (int rr = 0; rr < 4; rr++) { av[rr] = av2[rr]; bv[rr] = bv2[rr]; }
    }

    __syncthreads();
    float* red = lds;
#pragma unroll
    for (int ii = 0; ii < 4; ii++)
        *(float4*)(red + w * 1024 + (rg * 4 + ii) * 32 + cg * 4) = acc[ii];
    __syncthreads();

    int r = t >> 3, c4 = (t & 7) * 4;
    float4 s0 = *(const float4*)(red + r * 32 + c4);
    float4 s1 = *(const float4*)(red + 1024 + r * 32 + c4);
    float4 s2 = *(const float4*)(red + 2048 + r * 32 + c4);
    float4 s3 = *(const float4*)(red + 3072 + r * 32 + c4);
    float4 v;
    v.x = s0.x + s1.x + s2.x + s3.x;
    v.y = s0.y + s1.y + s2.y + s3.y;
    v.z = s0.z + s1.z + s2.z + s3.z;
    v.w = s0.w + s1.w + s2.w + s3.w;
    if (MODE == 0) {
        v.x = fmaxf(v.x, 0.f); v.y = fmaxf(v.y, 0.f);
        v.z = fmaxf(v.z, 0.f); v.w = fmaxf(v.w, 0.f);
    } else {
        v.x = 1.0f / (1.0f + expf(-v.x)); v.y = 1.0f / (1.0f + expf(-v.y));
        v.z = 1.0f / (1.0f + expf(-v.z)); v.w = 1.0f / (1.0f + expf(-v.w));
    }
    *(float4*)(C + (size_t)(row0 + r) * NC + col0 + c4) = v;
}

// ---------------------------------------------------------------------------
// P5: per (b,m): att = softmax_j( mask ? e2 : -1e12 ); out = att @ y; stats2.
__device__ __forceinline__ void phase5(
    SharedU& su, const float* __restrict__ E2,
    const unsigned int* __restrict__ maskbits, const float* __restrict__ y_g,
    float* __restrict__ att_out, float* __restrict__ stats, int bm, int t)
{
    float* att_s = su.p5.att_s;
    float* y_sh  = su.p5.y_sh;
    float* redS  = su.p5.redS;
    float* redQ  = su.p5.redQ;

    const float4* ysrc = (const float4*)(y_g + (size_t)bm * 4096);
    float4* yds = (float4*)y_sh;
    for (int i = t; i < 1024; i += 256) yds[i] = ysrc[i];

    {
        int r = t >> 3, j0 = (t & 7) * 4;
        unsigned int mk = maskbits[bm * 32 + r];
        float4 e4 = *(const float4*)(E2 + (size_t)bm * 1024 + r * 32 + j0);
        float v0 = ((mk >> (j0 + 0)) & 1u) ? e4.x : -1e12f;
        float v1 = ((mk >> (j0 + 1)) & 1u) ? e4.y : -1e12f;
        float v2 = ((mk >> (j0 + 2)) & 1u) ? e4.z : -1e12f;
        float v3 = ((mk >> (j0 + 3)) & 1u) ? e4.w : -1e12f;
        float mx = fmaxf(fmaxf(v0, v1), fmaxf(v2, v3));
#pragma unroll
        for (int off = 1; off < 8; off <<= 1) mx = fmaxf(mx, __shfl_xor(mx, off, 8));
        float e0 = __expf(v0 - mx), e1 = __expf(v1 - mx);
        float e2 = __expf(v2 - mx), e3 = __expf(v3 - mx);
        float s = e0 + e1 + e2 + e3;
#pragma unroll
        for (int off = 1; off < 8; off <<= 1) s += __shfl_xor(s, off, 8);
        float inv = 1.0f / s;
        att_s[r * 33 + j0 + 0] = e0 * inv;
        att_s[r * 33 + j0 + 1] = e1 * inv;
        att_s[r * 33 + j0 + 2] = e2 * inv;
        att_s[r * 33 + j0 + 3] = e3 * inv;
    }
    __syncthreads();

    int tx = t & 31, ty = t >> 5;
    int dq = tx * 4;
    float ssum = 0.f, sq = 0.f;
#pragma unroll
    for (int ii = 0; ii < 4; ii++) {
        int i = ty * 4 + ii;
        float4 acc = make_float4(0.f, 0.f, 0.f, 0.f);
        for (int j = 0; j < 32; j++) {
            float aw = att_s[i * 33 + j];
            float4 yv = *(const float4*)(y_sh + j * 128 + dq);
            acc.x += aw * yv.x; acc.y += aw * yv.y;
            acc.z += aw * yv.z; acc.w += aw * yv.w;
        }
        *(float4*)(att_out + (size_t)bm * 4096 + i * 128 + dq) = acc;
        ssum += acc.x + acc.y + acc.z + acc.w;
        sq   += acc.x * acc.x + acc.y * acc.y + acc.z * acc.z + acc.w * acc.w;
    }
#pragma unroll
    for (int off = 32; off > 0; off >>= 1) {
        ssum += __shfl_down(ssum, off, 64);
        sq   += __shfl_down(sq, off, 64);
    }
    int wave = t >> 6, lane = t & 63;
    if (lane == 0) { redS[wave] = ssum; redQ[wave] = sq; }
    __syncthreads();
    if (t == 0) {
        float S = redS[0] + redS[1] + redS[2] + redS[3];
        float Q = redQ[0] + redQ[1] + redQ[2] + redQ[3];
        int m = bm & 63;
        atomicAdd(&stats[384 + m], S);
        atomicAdd(&stats[448 + m], Q);
    }
}

// ---------------------------------------------------------------------------
// P6: per (b,n): z = relu(bn2(att_out)); 3x3 depthwise conv; stats3.
__device__ __forceinline__ void phase6(
    SharedU& su, const float* __restrict__ att_out, const float* __restrict__ Wdw,
    const float* __restrict__ g2, const float* __restrict__ b2,
    float* __restrict__ stats, float* __restrict__ v_g, int bn, int t)
{
    float* z_s = su.p6.z_s;
    float* a2_s = su.p6.a2_s;
    float* c2_s = su.p6.c2_s;
    float* redS = su.p6.redS;
    float* redQ = su.p6.redQ;
    int b = bn >> 5, n = bn & 31;

    if (t < 64) {
        float mean = stats[384 + t] * (1.0f / 32768.0f);
        float var  = stats[448 + t] * (1.0f / 32768.0f) - mean * mean;
        float a = g2[t] * rsqrtf(var + EPS);
        a2_s[t] = a; c2_s[t] = b2[t] - a * mean;
    }
    for (int i = t; i < 66 * 130; i += 256) z_s[i] = 0.f;
    __syncthreads();

    for (int i = t; i < 2048; i += 256) {
        int m = i >> 5, c4 = (i & 31) * 4;
        float4 vv = *(const float4*)(att_out + (((size_t)(b * 64 + m)) * 32 + n) * 128 + c4);
        float a = a2_s[m], c = c2_s[m];
        float* dst = z_s + (m + 1) * 130 + c4 + 1;
        dst[0] = fmaxf(a * vv.x + c, 0.f);
        dst[1] = fmaxf(a * vv.y + c, 0.f);
        dst[2] = fmaxf(a * vv.z + c, 0.f);
        dst[3] = fmaxf(a * vv.w + c, 0.f);
    }
    float w[9];
#pragma unroll
    for (int i = 0; i < 9; i++) w[i] = Wdw[n * 9 + i];
    __syncthreads();

    int tx = t & 31, ty = t >> 5;
    int d0 = tx * 4;
    float ssum = 0.f, sq = 0.f;
#pragma unroll
    for (int rr = 0; rr < 8; rr++) {
        int h = ty * 8 + rr;
        float o0 = 0.f, o1 = 0.f, o2 = 0.f, o3 = 0.f;
#pragma unroll
        for (int dh = 0; dh < 3; dh++) {
            const float* zr = z_s + (h + dh) * 130 + d0;
#pragma unroll
            for (int dw = 0; dw < 3; dw++) {
                float wv = w[dh * 3 + dw];
                o0 += wv * zr[dw + 0];
                o1 += wv * zr[dw + 1];
                o2 += wv * zr[dw + 2];
                o3 += wv * zr[dw + 3];
            }
        }
        *(float4*)(v_g + ((size_t)bn * 64 + h) * 128 + d0) = make_float4(o0, o1, o2, o3);
        ssum += o0 + o1 + o2 + o3;
        sq   += o0 * o0 + o1 * o1 + o2 * o2 + o3 * o3;
    }
#pragma unroll
    for (int off = 32; off > 0; off >>= 1) {
        ssum += __shfl_down(ssum, off, 64);
        sq   += __shfl_down(sq, off, 64);
    }
    int wave = t >> 6, lane = t & 63;
    if (lane == 0) { redS[wave] = ssum; redQ[wave] = sq; }
    __syncthreads();
    if (t == 0) {
        atomicAdd(&stats[512 + n], redS[0] + redS[1] + redS[2] + redS[3]);
        atomicAdd(&stats[544 + n], redQ[0] + redQ[1] + redQ[2] + redQ[3]);
    }
}

// ---------------------------------------------------------------------------
// P7: out[b,n,o,d] = sum_m Wl3[o,m]*relu(bn3(v[b,n,m,d])) + bn_sc(t_sc)
__device__ __forceinline__ void phase7(
    SharedU& su, const float* __restrict__ v_g, const float* __restrict__ t_sc,
    const float* __restrict__ Wl3, const float* __restrict__ g3,
    const float* __restrict__ b3, const float* __restrict__ gsc,
    const float* __restrict__ bsc, const float* __restrict__ stats,
    float* __restrict__ outp, int oh, int bn, int t)
{
    float* z_s  = su.p7.z_s;
    float* s_wT = su.p7.s_wT;
    int b = bn >> 5, n = bn & 31;

    float mean3 = stats[512 + n] * (1.0f / 65536.0f);
    float var3  = stats[544 + n] * (1.0f / 65536.0f) - mean3 * mean3;
    float a3 = g3[n] * rsqrtf(var3 + EPS);
    float c3 = b3[n] - a3 * mean3;

    const float4* vsrc = (const float4*)(v_g + (size_t)bn * 8192);
    for (int i = t; i < 2048; i += 256) {
        float4 vv = vsrc[i];
        float4 r;
        r.x = fmaxf(a3 * vv.x + c3, 0.f);
        r.y = fmaxf(a3 * vv.y + c3, 0.f);
        r.z = fmaxf(a3 * vv.z + c3, 0.f);
        r.w = fmaxf(a3 * vv.w + c3, 0.f);
        ((float4*)z_s)[i] = r;
    }
    const float* wbase = Wl3 + (size_t)oh * 64 * 64;
    for (int i = t; i < 1024; i += 256) {
        int m = i >> 4, rq = (i & 15) * 4;
        float4 wv;
        wv.x = wbase[(size_t)(rq + 0) * 64 + m];
        wv.y = wbase[(size_t)(rq + 1) * 64 + m];
        wv.z = wbase[(size_t)(rq + 2) * 64 + m];
        wv.w = wbase[(size_t)(rq + 3) * 64 + m];
        *(float4*)(s_wT + m * 68 + rq) = wv;
    }
    __syncthreads();

    int wv = t >> 6, lane = t & 63;
    int dl = lane & 15, g4 = lane >> 4;
    int d0 = dl * 8;
    int c0 = wv * 16 + g4 * 4;

    float4 acc[4][2];
#pragma unroll
    for (int i = 0; i < 4; i++) { acc[i][0] = make_float4(0,0,0,0); acc[i][1] = make_float4(0,0,0,0); }

    for (int m = 0; m < 64; m += 2) {
        float4 x00 = *(const float4*)(z_s + m * 128 + d0);
        float4 x01 = *(const float4*)(z_s + m * 128 + d0 + 4);
        float4 x10 = *(const float4*)(z_s + (m + 1) * 128 + d0);
        float4 x11 = *(const float4*)(z_s + (m + 1) * 128 + d0 + 4);
        float4 w0 = *(const float4*)(s_wT + m * 68 + c0);
        float4 w1 = *(const float4*)(s_wT + (m + 1) * 68 + c0);
        fma4(acc[0][0], w0.x, x00); fma4(acc[0][1], w0.x, x01);
        fma4(acc[1][0], w0.y, x00); fma4(acc[1][1], w0.y, x01);
        fma4(acc[2][0], w0.z, x00); fma4(acc[2][1], w0.z, x01);
        fma4(acc[3][0], w0.w, x00); fma4(acc[3][1], w0.w, x01);
        fma4(acc[0][0], w1.x, x10); fma4(acc[0][1], w1.x, x11);
        fma4(acc[1][0], w1.y, x10); fma4(acc[1][1], w1.y, x11);
        fma4(acc[2][0], w1.z, x10); fma4(acc[2][1], w1.z, x11);
        fma4(acc[3][0], w1.w, x10); fma4(acc[3][1], w1.w, x11);
    }

#pragma unroll
    for (int i = 0; i < 4; i++) {
        int o = oh * 64 + c0 + i;
        float msc = stats[o] * (1.0f / 32768.0f);
        float vsc = stats[128 + o] * (1.0f / 32768.0f) - msc * msc;
        float asc = gsc[o] * rsqrtf(vsc + EPS);
        float csc = bsc[o] - asc * msc;
        const float* ts = t_sc + (((size_t)(b * 128 + o)) * 32 + n) * 128 + d0;
        float4 t0 = *(const float4*)(ts);
        float4 t1 = *(const float4*)(ts + 4);
        float4 o0 = acc[i][0], o1 = acc[i][1];
        o0.x += asc * t0.x + csc; o0.y += asc * t0.y + csc;
        o0.z += asc * t0.z + csc; o0.w += asc * t0.w + csc;
        o1.x += asc * t1.x + csc; o1.y += asc * t1.y + csc;
        o1.z += asc * t1.z + csc; o1.w += asc * t1.w + csc;
        float* dst = outp + (((size_t)(b * 32 + n)) * 128 + o) * 128 + d0;
        *(float4*)dst = o0;
        *(float4*)(dst + 4) = o1;
    }
}

// ---------------------------------------------------------------------------
// Mega cooperative kernel: grid-size agnostic (256 or 512 blocks).
__global__ __launch_bounds__(256, 2) void mega(
    const float* x, const float* Wsc, const float* gsc, const float* bsc,
    const float* Wl1, const float* g1, const float* b1,
    const float* Wfc1, const float* Wfc2, const float* g2, const float* b2,
    const float* Wdw, const float* g3, const float* b3, const float* Wl3,
    float* stats, float* t_sc, float* t_l1, float* y_g,
    float* E, float* H, float* E2, unsigned int* maskb, float* outp)
{
    __shared__ SharedU su;
    cg::grid_group grid = cg::this_grid();
    int blk = blockIdx.x;
    int t = threadIdx.x;
    int gsz = gridDim.x;

    for (int u = blk; u < 768; u += gsz) {
        phase1(su, x, Wsc, Wl1, t_sc, t_l1, stats, u >> 8, u & 255, t);
        __syncthreads();
    }
    grid.sync();

    for (int u = blk; u < 512; u += gsz) {
        phase2(su, t_l1, g1, b1, stats, y_g, E, maskb, u, t);
        __syncthreads();
    }
    grid.sync();

    for (int u = blk; u < 256; u += gsz) {
        gemm_phase<1024, 0>(su, E, Wfc1, H, 512, u & 15, u >> 4, t);
        __syncthreads();
    }
    grid.sync();

    for (int u = blk; u < 512; u += gsz) {
        gemm_phase<512, 1>(su, H, Wfc2, E2, 1024, u & 31, u >> 5, t);
        __syncthreads();
    }
    grid.sync();

    for (int u = blk; u < 512; u += gsz) {
        phase5(su, E2, maskb, y_g, t_l1, stats, u, t);
        __syncthreads();
    }
    grid.sync();

    for (int u = blk; u < 256; u += gsz) {
        phase6(su, t_l1, Wdw, g2, b2, stats, y_g, u, t);
        __syncthreads();
    }
    grid.sync();

    for (int u = blk; u < 512; u += gsz) {
        phase7(su, y_g, t_sc, Wl3, g3, b3, gsc, bsc, stats, outp, u & 1, u >> 1, t);
        __syncthreads();
    }
}

// ---------------------------------------------------------------------------
// Fallback wrappers (round-3 structure, same phase bodies).
__global__ __launch_bounds__(256) void k1_w(
    const float* __restrict__ x, const float* __restrict__ Wsc,
    const float* __restrict__ Wl1, float* __restrict__ t_sc,
    float* __restrict__ t_l1, float* __restrict__ stats)
{
    __shared__ SharedU su;
    phase1(su, x, Wsc, Wl1, t_sc, t_l1, stats, blockIdx.x, blockIdx.y, threadIdx.x);
}
__global__ __launch_bounds__(256) void k2_w(
    const float* __restrict__ t_l1, const float* __restrict__ g1,
    const float* __restrict__ b1, const float* __restrict__ stats,
    float* __restrict__ y_g, float* __restrict__ E,
    unsigned int* __restrict__ maskbits)
{
    __shared__ SharedU su;
    phase2(su, t_l1, g1, b1, stats, y_g, E, maskbits, blockIdx.x, threadIdx.x);
}
template<int KDIM, int MODE>
__global__ __launch_bounds__(256) void k3_w(
    const float* __restrict__ A, const float* __restrict__ Bm,
    float* __restrict__ C, int NC)
{
    __shared__ SharedU su;
    gemm_phase<KDIM, MODE>(su, A, Bm, C, NC, blockIdx.x, blockIdx.y, threadIdx.x);
}
__global__ __launch_bounds__(256) void k5_w(
    const float* __restrict__ E2, const unsigned int* __restrict__ maskbits,
    const float* __restrict__ y_g, float* __restrict__ att_out,
    float* __restrict__ stats)
{
    __shared__ SharedU su;
    phase5(su, E2, maskbits, y_g, att_out, stats, blockIdx.x, threadIdx.x);
}
__global__ __launch_bounds__(256) void k6_w(
    const float* __restrict__ att_out, const float* __restrict__ Wdw,
    const float* __restrict__ g2, const float* __restrict__ b2,
    float* __restrict__ stats, float* __restrict__ v_g)
{
    __shared__ SharedU su;
    phase6(su, att_out, Wdw, g2, b2, stats, v_g, blockIdx.x, threadIdx.x);
}
__global__ __launch_bounds__(256) void k7_w(
    const float* __restrict__ v_g, const float* __restrict__ t_sc,
    const float* __restrict__ Wl3, const float* __restrict__ g3,
    const float* __restrict__ b3, const float* __restrict__ gsc,
    const float* __restrict__ bsc, const float* __restrict__ stats,
    float* __restrict__ outp)
{
    __shared__ SharedU su;
    phase7(su, v_g, t_sc, Wl3, g3, b3, gsc, bsc, stats, outp,
           blockIdx.x, blockIdx.y, threadIdx.x);
}

// ---------------------------------------------------------------------------
extern "C" void kernel_launch(void* const* d_in, const int* in_sizes, int n_in,
                              void* d_out, int out_size, void* d_ws, size_t ws_size,
                              hipStream_t stream)
{
    const float* x    = (const float*)d_in[0];
    const float* Wsc  = (const float*)d_in[1];
    const float* gsc  = (const float*)d_in[2];
    const float* bsc  = (const float*)d_in[3];
    const float* Wl1  = (const float*)d_in[4];
    const float* g1   = (const float*)d_in[5];
    const float* b1   = (const float*)d_in[6];
    const float* Wfc1 = (const float*)d_in[7];
    const float* Wfc2 = (const float*)d_in[8];
    const float* g2   = (const float*)d_in[9];
    const float* b2   = (const float*)d_in[10];
    const float* Wdw  = (const float*)d_in[11];
    const float* g3   = (const float*)d_in[12];
    const float* b3   = (const float*)d_in[13];
    const float* Wl3  = (const float*)d_in[14];
    float* outp = (float*)d_out;

    float* ws = (float*)d_ws;
    float* stats = ws;                          // 1024
    float* t_sc  = ws + 1024;                   // 4194304
    float* t_l1  = t_sc + 4194304;              // 2097152 (reused as att_out)
    float* y_g   = t_l1 + 2097152;              // 2097152 (reused as conv out)
    float* E     = y_g + 2097152;               // 524288
    float* H     = E + 524288;                  // 262144
    float* E2    = H + 262144;                  // 524288
    unsigned int* maskb = (unsigned int*)(E2 + 524288);  // 16384 u32

    (void)hipMemsetAsync(stats, 0, 1024 * sizeof(float), stream);

    // Pick coop grid from the runtime's own occupancy model (pure query,
    // graph-capture safe): 512 blocks if >=2 blocks/CU, else 256.
    int perCU = 0;
    hipError_t qerr = hipOccupancyMaxActiveBlocksPerMultiprocessor(&perCU, mega, 256, 0);
    int nblk = (qerr == hipSuccess && perCU >= 2) ? 512 : 256;

    void* args[] = {
        (void*)&x, (void*)&Wsc, (void*)&gsc, (void*)&bsc, (void*)&Wl1,
        (void*)&g1, (void*)&b1, (void*)&Wfc1, (void*)&Wfc2, (void*)&g2,
        (void*)&b2, (void*)&Wdw, (void*)&g3, (void*)&b3, (void*)&Wl3,
        (void*)&stats, (void*)&t_sc, (void*)&t_l1, (void*)&y_g,
        (void*)&E, (void*)&H, (void*)&E2, (void*)&maskb, (void*)&outp
    };
    hipError_t lerr = hipLaunchCooperativeKernel((void*)mega, dim3(nblk), dim3(256),
                                                 args, 0, stream);
    if (lerr != hipSuccess) {
        // Fallback: proven multi-kernel sequence (identical math).
        k1_w<<<dim3(3, 256), 256, 0, stream>>>(x, Wsc, Wl1, t_sc, t_l1, stats);
        k2_w<<<512, 256, 0, stream>>>(t_l1, g1, b1, stats, y_g, E, maskb);
        k3_w<1024, 0><<<dim3(16, 16), 256, 0, stream>>>(E, Wfc1, H, 512);
        k3_w<512, 1><<<dim3(32, 16), 256, 0, stream>>>(H, Wfc2, E2, 1024);
        k5_w<<<512, 256, 0, stream>>>(E2, maskb, y_g, t_l1, stats);
        k6_w<<<256, 256, 0, stream>>>(t_l1, Wdw, g2, b2, stats, y_g);
        k7_w<<<dim3(2, 256), 256, 0, stream>>>(y_g, t_sc, Wl3, g3, b3, gsc, bsc, stats, outp);
    }
}

// Round 6
// 256.346 us; speedup vs baseline: 1.7317x; 1.7317x over previous
//
#include <hip/hip_runtime.h>
#include <math.h>

// B=8, N=32, M=64, D=128, OUT=128, K=3, P=N*N=1024, r=512
#define EPS 1e-5f

// stats layout (floats) in ws[0..1023]:
//  [0..127]   sum_sc   [128..255] sq_sc
//  [256..319] sum1     [320..383] sq1
//  [384..447] sum2     [448..511] sq2
//  [512..543] sum3     [544..575] sq3

__device__ __forceinline__ void fma4(float4& a, float s, const float4& v) {
    a.x += s * v.x; a.y += s * v.y; a.z += s * v.z; a.w += s * v.w;
}

// Shared-memory union (max 50176 B).
union SharedU {
    struct { float s_x[64 * 128]; float s_wT[64 * 68]; } p1;          // 50176 B
    struct { float y_s[32 * 132]; float S_s[32]; unsigned int m_s[32]; } p2;
    struct { float lds[4 * 2304]; } p3;                                // 36864 B
    struct { float att_s[32 * 33]; float y_sh[32 * 128]; float redS[4], redQ[4]; } p5;
    struct { float z_s[66 * 130]; float a2_s[64], c2_s[64]; float redS[4], redQ[4]; } p6;
    struct { float z_s[64 * 128]; float s_wT[64 * 68]; } p7;           // 50176 B
};

// ---------------------------------------------------------------------------
// P1: one 64-channel group of { t_sc = Wsc @ xm (g=0,1) ; t_l1 = Wl1 @ xm (g=2) }
__device__ __forceinline__ void phase1(
    SharedU& su, const float* __restrict__ x, const float* __restrict__ Wsc,
    const float* __restrict__ Wl1, float* __restrict__ t_sc,
    float* __restrict__ t_l1, float* __restrict__ stats, int g, int bn, int t)
{
    float* s_x  = su.p1.s_x;
    float* s_wT = su.p1.s_wT;
    int b = bn >> 5, n = bn & 31;

    const float4* xg = (const float4*)(x + (size_t)bn * 8192);
    for (int i = t; i < 2048; i += 256) ((float4*)s_x)[i] = xg[i];

    const float* wbase = (g < 2) ? (Wsc + (size_t)g * 64 * 64) : Wl1;
    for (int i = t; i < 1024; i += 256) {
        int m = i >> 4, rq = (i & 15) * 4;
        float4 wv;
        wv.x = wbase[(size_t)(rq + 0) * 64 + m];
        wv.y = wbase[(size_t)(rq + 1) * 64 + m];
        wv.z = wbase[(size_t)(rq + 2) * 64 + m];
        wv.w = wbase[(size_t)(rq + 3) * 64 + m];
        *(float4*)(s_wT + m * 68 + rq) = wv;
    }
    __syncthreads();

    int wv = t >> 6, lane = t & 63;
    int dl = lane & 15;
    int g4 = lane >> 4;
    int d0 = dl * 8;
    int c0 = wv * 16 + g4 * 4;

    float4 acc[4][2];
#pragma unroll
    for (int i = 0; i < 4; i++) { acc[i][0] = make_float4(0,0,0,0); acc[i][1] = make_float4(0,0,0,0); }

    for (int m = 0; m < 64; m += 2) {
        float4 x00 = *(const float4*)(s_x + m * 128 + d0);
        float4 x01 = *(const float4*)(s_x + m * 128 + d0 + 4);
        float4 x10 = *(const float4*)(s_x + (m + 1) * 128 + d0);
        float4 x11 = *(const float4*)(s_x + (m + 1) * 128 + d0 + 4);
        float4 w0 = *(const float4*)(s_wT + m * 68 + c0);
        float4 w1 = *(const float4*)(s_wT + (m + 1) * 68 + c0);
        fma4(acc[0][0], w0.x, x00); fma4(acc[0][1], w0.x, x01);
        fma4(acc[1][0], w0.y, x00); fma4(acc[1][1], w0.y, x01);
        fma4(acc[2][0], w0.z, x00); fma4(acc[2][1], w0.z, x01);
        fma4(acc[3][0], w0.w, x00); fma4(acc[3][1], w0.w, x01);
        fma4(acc[0][0], w1.x, x10); fma4(acc[0][1], w1.x, x11);
        fma4(acc[1][0], w1.y, x10); fma4(acc[1][1], w1.y, x11);
        fma4(acc[2][0], w1.z, x10); fma4(acc[2][1], w1.z, x11);
        fma4(acc[3][0], w1.w, x10); fma4(acc[3][1], w1.w, x11);
    }

#pragma unroll
    for (int i = 0; i < 4; i++) {
        int cc = g * 64 + c0 + i;
        float4 v0 = acc[i][0], v1 = acc[i][1];
        float* dst;
        if (cc < 128) dst = t_sc + (((size_t)(b * 128 + cc)) * 32 + n) * 128 + d0;
        else          dst = t_l1 + (((size_t)(b * 64 + (cc - 128))) * 32 + n) * 128 + d0;
        *(float4*)dst = v0;
        *(float4*)(dst + 4) = v1;
        float s = v0.x + v0.y + v0.z + v0.w + v1.x + v1.y + v1.z + v1.w;
        float q = v0.x*v0.x + v0.y*v0.y + v0.z*v0.z + v0.w*v0.w
                + v1.x*v1.x + v1.y*v1.y + v1.z*v1.z + v1.w*v1.w;
#pragma unroll
        for (int off = 8; off > 0; off >>= 1) {
            s += __shfl_down(s, off, 16);
            q += __shfl_down(q, off, 16);
        }
        if (dl == 0) {
            if (cc < 128) {
                atomicAdd(&stats[cc], s);
                atomicAdd(&stats[cc + 128], q);
            } else {
                atomicAdd(&stats[256 + (cc - 128)], s);
                atomicAdd(&stats[320 + (cc - 128)], q);
            }
        }
    }
}

// ---------------------------------------------------------------------------
// P2: per (b,m): y = bn1(t_l1); row sums; dot/eq pairs; E; maskbits; store y.
__device__ __forceinline__ void phase2(
    SharedU& su, const float* __restrict__ t_l1, const float* __restrict__ g1,
    const float* __restrict__ b1, const float* __restrict__ stats,
    float* __restrict__ y_g, float* __restrict__ E,
    unsigned int* __restrict__ maskbits, int bm, int t)
{
    float* y_s = su.p2.y_s;
    float* S_s = su.p2.S_s;
    unsigned int* m_s = su.p2.m_s;
    int m = bm & 63;
    float mean = stats[256 + m] * (1.0f / 32768.0f);
    float var  = stats[320 + m] * (1.0f / 32768.0f) - mean * mean;
    float a = g1[m] * rsqrtf(var + EPS);
    float c = b1[m] - a * mean;

    if (t < 32) m_s[t] = 0u;
    const float4* src = (const float4*)(t_l1 + (size_t)bm * 4096);
    for (int i = t; i < 1024; i += 256) {
        float4 v = src[i];
        v.x = a * v.x + c; v.y = a * v.y + c; v.z = a * v.z + c; v.w = a * v.w + c;
        int row = i >> 5, col = (i & 31) * 4;
        *(float4*)(y_s + row * 132 + col) = v;
    }
    __syncthreads();

    {   // row sums
        int r = t >> 3, j = t & 7;
        float s = 0.f;
        const float* yr = y_s + r * 132 + j * 16;
#pragma unroll
        for (int dd = 0; dd < 16; dd++) s += yr[dd];
#pragma unroll
        for (int off = 4; off > 0; off >>= 1) s += __shfl_down(s, off, 8);
        if (j == 0) S_s[r] = s;
    }
    __syncthreads();

    int i = t >> 3, j0 = (t & 7) * 4;
    float dot[4] = {0.f, 0.f, 0.f, 0.f};
    float eqs[4] = {0.f, 0.f, 0.f, 0.f};
    const float* yi = y_s + i * 132;
    for (int dq = 0; dq < 32; dq++) {
        float4 a4 = *(const float4*)(yi + dq * 4);
#pragma unroll
        for (int q = 0; q < 4; q++) {
            float4 b4 = *(const float4*)(y_s + (j0 + q) * 132 + dq * 4);
            dot[q] += a4.x * b4.x + a4.y * b4.y + a4.z * b4.z + a4.w * b4.w;
            eqs[q] += (a4.x == b4.x ? b4.x : 0.f) + (a4.y == b4.y ? b4.y : 0.f)
                    + (a4.z == b4.z ? b4.z : 0.f) + (a4.w == b4.w ? b4.w : 0.f);
        }
    }
    float Si = S_s[i];
    unsigned int bits = 0u;
    float ev[4];
#pragma unroll
    for (int q = 0; q < 4; q++) {
        float Sj = S_s[j0 + q];
        float num = dot[q] - Si * Sj * (1.0f / 128.0f);
        if (num > 0.f) bits |= (1u << (j0 + q));
        ev[q] = (Si + 2.f * Sj - eqs[q]) * (1.0f / 256.0f);
    }
    atomicOr(&m_s[i], bits);
    *(float4*)(E + (size_t)bm * 1024 + i * 32 + j0) = make_float4(ev[0], ev[1], ev[2], ev[3]);
    __syncthreads();
    if (t < 32) maskbits[bm * 32 + t] = m_s[t];

    float4* yd = (float4*)(y_g + (size_t)bm * 4096);
    for (int idx = t; idx < 1024; idx += 256) {
        int row = idx >> 5, col = (idx & 31) * 4;
        yd[idx] = *(const float4*)(y_s + row * 132 + col);
    }
}

// ---------------------------------------------------------------------------
// GEMM phase: C[r,c] = epi( sum_k A[r,k] * Bm[c,k] ). 32x32 tile, in-block
// wave split-K (4 waves, wave-private LDS slabs). MODE 0: relu, 1: sigmoid.
template<int KDIM, int MODE>
__device__ __forceinline__ void gemm_phase(
    SharedU& su, const float* __restrict__ A, const float* __restrict__ Bm,
    float* __restrict__ C, int NC, int ct, int rt, int t)
{
    float* lds = su.p3.lds;
    int w = t >> 6, l = t & 63;
    int row0 = rt * 32, col0 = ct * 32;
    float* As = lds + w * 2304;
    float* Bs = As + 1152;
    int rg = l >> 3;
    int cg = l & 7;
    int kq = (l & 7) * 4;
    constexpr int SLABS = KDIM / 128;

    float4 acc[4];
#pragma unroll
    for (int ii = 0; ii < 4; ii++) acc[ii] = make_float4(0,0,0,0);

    float4 av[4], bv[4], av2[4], bv2[4];
    int k0 = w * 32;
#pragma unroll
    for (int rr = 0; rr < 4; rr++) {
        int r = rg + rr * 8;
        av[rr] = *(const float4*)(A  + (size_t)(row0 + r) * KDIM + k0 + kq);
        bv[rr] = *(const float4*)(Bm + (size_t)(col0 + r) * KDIM + k0 + kq);
    }

    for (int s = 0; s < SLABS; s++) {
#pragma unroll
        for (int rr = 0; rr < 4; rr++) {
            int r = rg + rr * 8;
            As[(kq + 0) * 36 + r] = av[rr].x; As[(kq + 1) * 36 + r] = av[rr].y;
            As[(kq + 2) * 36 + r] = av[rr].z; As[(kq + 3) * 36 + r] = av[rr].w;
            Bs[(kq + 0) * 36 + r] = bv[rr].x; Bs[(kq + 1) * 36 + r] = bv[rr].y;
            Bs[(kq + 2) * 36 + r] = bv[rr].z; Bs[(kq + 3) * 36 + r] = bv[rr].w;
        }
        if (s + 1 < SLABS) {
            int kn = (4 * (s + 1) + w) * 32;
#pragma unroll
            for (int rr = 0; rr < 4; rr++) {
                int r = rg + rr * 8;
                av2[rr] = *(const float4*)(A  + (size_t)(row0 + r) * KDIM + kn + kq);
                bv2[rr] = *(const float4*)(Bm + (size_t)(col0 + r) * KDIM + kn + kq);
            }
        }
#pragma unroll
        for (int k = 0; k < 32; k++) {
            float4 a = *(const float4*)(As + k * 36 + rg * 4);
            float4 b = *(const float4*)(Bs + k * 36 + cg * 4);
            fma4(acc[0], a.x, b);
            fma4(acc[1], a.y, b);
            fma4(acc[2], a.z, b);
            fma4(acc[3], a.w, b);
        }
#pragma unroll
        for (int rr = 0; rr < 4; rr++) { av[rr] = av2[rr]; bv[rr] = bv2[rr]; }
    }

    __syncthreads();
    float* red = lds;
#pragma unroll
    for (int ii = 0; ii < 4; ii++)
        *(float4*)(red + w * 1024 + (rg * 4 + ii) * 32 + cg * 4) = acc[ii];
    __syncthreads();

    int r = t >> 3, c4 = (t & 7) * 4;
    float4 s0 = *(const float4*)(red + r * 32 + c4);
    float4 s1 = *(const float4*)(red + 1024 + r * 32 + c4);
    float4 s2 = *(const float4*)(red + 2048 + r * 32 + c4);
    float4 s3 = *(const float4*)(red + 3072 + r * 32 + c4);
    float4 v;
    v.x = s0.x + s1.x + s2.x + s3.x;
    v.y = s0.y + s1.y + s2.y + s3.y;
    v.z = s0.z + s1.z + s2.z + s3.z;
    v.w = s0.w + s1.w + s2.w + s3.w;
    if (MODE == 0) {
        v.x = fmaxf(v.x, 0.f); v.y = fmaxf(v.y, 0.f);
        v.z = fmaxf(v.z, 0.f); v.w = fmaxf(v.w, 0.f);
    } else {
        v.x = 1.0f / (1.0f + expf(-v.x)); v.y = 1.0f / (1.0f + expf(-v.y));
        v.z = 1.0f / (1.0f + expf(-v.z)); v.w = 1.0f / (1.0f + expf(-v.w));
    }
    *(float4*)(C + (size_t)(row0 + r) * NC + col0 + c4) = v;
}

// ---------------------------------------------------------------------------
// P5: per (b,m): att = softmax_j( mask ? e2 : -1e12 ); out = att @ y; stats2.
__device__ __forceinline__ void phase5(
    SharedU& su, const float* __restrict__ E2,
    const unsigned int* __restrict__ maskbits, const float* __restrict__ y_g,
    float* __restrict__ att_out, float* __restrict__ stats, int bm, int t)
{
    float* att_s = su.p5.att_s;
    float* y_sh  = su.p5.y_sh;
    float* redS  = su.p5.redS;
    float* redQ  = su.p5.redQ;

    const float4* ysrc = (const float4*)(y_g + (size_t)bm * 4096);
    float4* yds = (float4*)y_sh;
    for (int i = t; i < 1024; i += 256) yds[i] = ysrc[i];

    {
        int r = t >> 3, j0 = (t & 7) * 4;
        unsigned int mk = maskbits[bm * 32 + r];
        float4 e4 = *(const float4*)(E2 + (size_t)bm * 1024 + r * 32 + j0);
        float v0 = ((mk >> (j0 + 0)) & 1u) ? e4.x : -1e12f;
        float v1 = ((mk >> (j0 + 1)) & 1u) ? e4.y : -1e12f;
        float v2 = ((mk >> (j0 + 2)) & 1u) ? e4.z : -1e12f;
        float v3 = ((mk >> (j0 + 3)) & 1u) ? e4.w : -1e12f;
        float mx = fmaxf(fmaxf(v0, v1), fmaxf(v2, v3));
#pragma unroll
        for (int off = 1; off < 8; off <<= 1) mx = fmaxf(mx, __shfl_xor(mx, off, 8));
        float e0 = __expf(v0 - mx), e1 = __expf(v1 - mx);
        float e2 = __expf(v2 - mx), e3 = __expf(v3 - mx);
        float s = e0 + e1 + e2 + e3;
#pragma unroll
        for (int off = 1; off < 8; off <<= 1) s += __shfl_xor(s, off, 8);
        float inv = 1.0f / s;
        att_s[r * 33 + j0 + 0] = e0 * inv;
        att_s[r * 33 + j0 + 1] = e1 * inv;
        att_s[r * 33 + j0 + 2] = e2 * inv;
        att_s[r * 33 + j0 + 3] = e3 * inv;
    }
    __syncthreads();

    int tx = t & 31, ty = t >> 5;
    int dq = tx * 4;
    float ssum = 0.f, sq = 0.f;
#pragma unroll
    for (int ii = 0; ii < 4; ii++) {
        int i = ty * 4 + ii;
        float4 acc = make_float4(0.f, 0.f, 0.f, 0.f);
        for (int j = 0; j < 32; j++) {
            float aw = att_s[i * 33 + j];
            float4 yv = *(const float4*)(y_sh + j * 128 + dq);
            acc.x += aw * yv.x; acc.y += aw * yv.y;
            acc.z += aw * yv.z; acc.w += aw * yv.w;
        }
        *(float4*)(att_out + (size_t)bm * 4096 + i * 128 + dq) = acc;
        ssum += acc.x + acc.y + acc.z + acc.w;
        sq   += acc.x * acc.x + acc.y * acc.y + acc.z * acc.z + acc.w * acc.w;
    }
#pragma unroll
    for (int off = 32; off > 0; off >>= 1) {
        ssum += __shfl_down(ssum, off, 64);
        sq   += __shfl_down(sq, off, 64);
    }
    int wave = t >> 6, lane = t & 63;
    if (lane == 0) { redS[wave] = ssum; redQ[wave] = sq; }
    __syncthreads();
    if (t == 0) {
        float S = redS[0] + redS[1] + redS[2] + redS[3];
        float Q = redQ[0] + redQ[1] + redQ[2] + redQ[3];
        int m = bm & 63;
        atomicAdd(&stats[384 + m], S);
        atomicAdd(&stats[448 + m], Q);
    }
}

// ---------------------------------------------------------------------------
// P6: per (b,n): z = relu(bn2(att_out)); 3x3 depthwise conv; stats3.
__device__ __forceinline__ void phase6(
    SharedU& su, const float* __restrict__ att_out, const float* __restrict__ Wdw,
    const float* __restrict__ g2, const float* __restrict__ b2,
    float* __restrict__ stats, float* __restrict__ v_g, int bn, int t)
{
    float* z_s = su.p6.z_s;
    float* a2_s = su.p6.a2_s;
    float* c2_s = su.p6.c2_s;
    float* redS = su.p6.redS;
    float* redQ = su.p6.redQ;
    int b = bn >> 5, n = bn & 31;

    if (t < 64) {
        float mean = stats[384 + t] * (1.0f / 32768.0f);
        float var  = stats[448 + t] * (1.0f / 32768.0f) - mean * mean;
        float a = g2[t] * rsqrtf(var + EPS);
        a2_s[t] = a; c2_s[t] = b2[t] - a * mean;
    }
    for (int i = t; i < 66 * 130; i += 256) z_s[i] = 0.f;
    __syncthreads();

    for (int i = t; i < 2048; i += 256) {
        int m = i >> 5, c4 = (i & 31) * 4;
        float4 vv = *(const float4*)(att_out + (((size_t)(b * 64 + m)) * 32 + n) * 128 + c4);
        float a = a2_s[m], c = c2_s[m];
        float* dst = z_s + (m + 1) * 130 + c4 + 1;
        dst[0] = fmaxf(a * vv.x + c, 0.f);
        dst[1] = fmaxf(a * vv.y + c, 0.f);
        dst[2] = fmaxf(a * vv.z + c, 0.f);
        dst[3] = fmaxf(a * vv.w + c, 0.f);
    }
    float w[9];
#pragma unroll
    for (int i = 0; i < 9; i++) w[i] = Wdw[n * 9 + i];
    __syncthreads();

    int tx = t & 31, ty = t >> 5;
    int d0 = tx * 4;
    float ssum = 0.f, sq = 0.f;
#pragma unroll
    for (int rr = 0; rr < 8; rr++) {
        int h = ty * 8 + rr;
        float o0 = 0.f, o1 = 0.f, o2 = 0.f, o3 = 0.f;
#pragma unroll
        for (int dh = 0; dh < 3; dh++) {
            const float* zr = z_s + (h + dh) * 130 + d0;
#pragma unroll
            for (int dw = 0; dw < 3; dw++) {
                float wv = w[dh * 3 + dw];
                o0 += wv * zr[dw + 0];
                o1 += wv * zr[dw + 1];
                o2 += wv * zr[dw + 2];
                o3 += wv * zr[dw + 3];
            }
        }
        *(float4*)(v_g + ((size_t)bn * 64 + h) * 128 + d0) = make_float4(o0, o1, o2, o3);
        ssum += o0 + o1 + o2 + o3;
        sq   += o0 * o0 + o1 * o1 + o2 * o2 + o3 * o3;
    }
#pragma unroll
    for (int off = 32; off > 0; off >>= 1) {
        ssum += __shfl_down(ssum, off, 64);
        sq   += __shfl_down(sq, off, 64);
    }
    int wave = t >> 6, lane = t & 63;
    if (lane == 0) { redS[wave] = ssum; redQ[wave] = sq; }
    __syncthreads();
    if (t == 0) {
        atomicAdd(&stats[512 + n], redS[0] + redS[1] + redS[2] + redS[3]);
        atomicAdd(&stats[544 + n], redQ[0] + redQ[1] + redQ[2] + redQ[3]);
    }
}

// ---------------------------------------------------------------------------
// P7: out[b,n,o,d] = sum_m Wl3[o,m]*relu(bn3(v[b,n,m,d])) + bn_sc(t_sc)
__device__ __forceinline__ void phase7(
    SharedU& su, const float* __restrict__ v_g, const float* __restrict__ t_sc,
    const float* __restrict__ Wl3, const float* __restrict__ g3,
    const float* __restrict__ b3, const float* __restrict__ gsc,
    const float* __restrict__ bsc, const float* __restrict__ stats,
    float* __restrict__ outp, int oh, int bn, int t)
{
    float* z_s  = su.p7.z_s;
    float* s_wT = su.p7.s_wT;
    int b = bn >> 5, n = bn & 31;

    float mean3 = stats[512 + n] * (1.0f / 65536.0f);
    float var3  = stats[544 + n] * (1.0f / 65536.0f) - mean3 * mean3;
    float a3 = g3[n] * rsqrtf(var3 + EPS);
    float c3 = b3[n] - a3 * mean3;

    const float4* vsrc = (const float4*)(v_g + (size_t)bn * 8192);
    for (int i = t; i < 2048; i += 256) {
        float4 vv = vsrc[i];
        float4 r;
        r.x = fmaxf(a3 * vv.x + c3, 0.f);
        r.y = fmaxf(a3 * vv.y + c3, 0.f);
        r.z = fmaxf(a3 * vv.z + c3, 0.f);
        r.w = fmaxf(a3 * vv.w + c3, 0.f);
        ((float4*)z_s)[i] = r;
    }
    const float* wbase = Wl3 + (size_t)oh * 64 * 64;
    for (int i = t; i < 1024; i += 256) {
        int m = i >> 4, rq = (i & 15) * 4;
        float4 wv;
        wv.x = wbase[(size_t)(rq + 0) * 64 + m];
        wv.y = wbase[(size_t)(rq + 1) * 64 + m];
        wv.z = wbase[(size_t)(rq + 2) * 64 + m];
        wv.w = wbase[(size_t)(rq + 3) * 64 + m];
        *(float4*)(s_wT + m * 68 + rq) = wv;
    }
    __syncthreads();

    int wv = t >> 6, lane = t & 63;
    int dl = lane & 15, g4 = lane >> 4;
    int d0 = dl * 8;
    int c0 = wv * 16 + g4 * 4;

    float4 acc[4][2];
#pragma unroll
    for (int i = 0; i < 4; i++) { acc[i][0] = make_float4(0,0,0,0); acc[i][1] = make_float4(0,0,0,0); }

    for (int m = 0; m < 64; m += 2) {
        float4 x00 = *(const float4*)(z_s + m * 128 + d0);
        float4 x01 = *(const float4*)(z_s + m * 128 + d0 + 4);
        float4 x10 = *(const float4*)(z_s + (m + 1) * 128 + d0);
        float4 x11 = *(const float4*)(z_s + (m + 1) * 128 + d0 + 4);
        float4 w0 = *(const float4*)(s_wT + m * 68 + c0);
        float4 w1 = *(const float4*)(s_wT + (m + 1) * 68 + c0);
        fma4(acc[0][0], w0.x, x00); fma4(acc[0][1], w0.x, x01);
        fma4(acc[1][0], w0.y, x00); fma4(acc[1][1], w0.y, x01);
        fma4(acc[2][0], w0.z, x00); fma4(acc[2][1], w0.z, x01);
        fma4(acc[3][0], w0.w, x00); fma4(acc[3][1], w0.w, x01);
        fma4(acc[0][0], w1.x, x10); fma4(acc[0][1], w1.x, x11);
        fma4(acc[1][0], w1.y, x10); fma4(acc[1][1], w1.y, x11);
        fma4(acc[2][0], w1.z, x10); fma4(acc[2][1], w1.z, x11);
        fma4(acc[3][0], w1.w, x10); fma4(acc[3][1], w1.w, x11);
    }

#pragma unroll
    for (int i = 0; i < 4; i++) {
        int o = oh * 64 + c0 + i;
        float msc = stats[o] * (1.0f / 32768.0f);
        float vsc = stats[128 + o] * (1.0f / 32768.0f) - msc * msc;
        float asc = gsc[o] * rsqrtf(vsc + EPS);
        float csc = bsc[o] - asc * msc;
        const float* ts = t_sc + (((size_t)(b * 128 + o)) * 32 + n) * 128 + d0;
        float4 t0 = *(const float4*)(ts);
        float4 t1 = *(const float4*)(ts + 4);
        float4 o0 = acc[i][0], o1 = acc[i][1];
        o0.x += asc * t0.x + csc; o0.y += asc * t0.y + csc;
        o0.z += asc * t0.z + csc; o0.w += asc * t0.w + csc;
        o1.x += asc * t1.x + csc; o1.y += asc * t1.y + csc;
        o1.z += asc * t1.z + csc; o1.w += asc * t1.w + csc;
        float* dst = outp + (((size_t)(b * 32 + n)) * 128 + o) * 128 + d0;
        *(float4*)dst = o0;
        *(float4*)(dst + 4) = o1;
    }
}

// ---------------------------------------------------------------------------
// Kernels. k1a: critical-path part of P1 (t_l1 only, g=2), grid 256.
__global__ __launch_bounds__(256) void k1a_w(
    const float* __restrict__ x, const float* __restrict__ Wsc,
    const float* __restrict__ Wl1, float* __restrict__ t_sc,
    float* __restrict__ t_l1, float* __restrict__ stats)
{
    __shared__ SharedU su;
    phase1(su, x, Wsc, Wl1, t_sc, t_l1, stats, 2, blockIdx.x, threadIdx.x);
}

__global__ __launch_bounds__(256) void k2_w(
    const float* __restrict__ t_l1, const float* __restrict__ g1,
    const float* __restrict__ b1, const float* __restrict__ stats,
    float* __restrict__ y_g, float* __restrict__ E,
    unsigned int* __restrict__ maskbits)
{
    __shared__ SharedU su;
    phase2(su, t_l1, g1, b1, stats, y_g, E, maskbits, blockIdx.x, threadIdx.x);
}

// k3p: blocks [0,256) = FC1 GEMM tiles; blocks [256,512) = P1 g=0 (t_sc lo).
__global__ __launch_bounds__(256) void k3p_w(
    const float* __restrict__ A, const float* __restrict__ Bm,
    float* __restrict__ C,
    const float* __restrict__ x, const float* __restrict__ Wsc,
    const float* __restrict__ Wl1, float* __restrict__ t_sc,
    float* __restrict__ t_l1, float* __restrict__ stats)
{
    __shared__ SharedU su;
    int blk = blockIdx.x;
    if (blk < 256) gemm_phase<1024, 0>(su, A, Bm, C, 512, blk & 15, blk >> 4, threadIdx.x);
    else           phase1(su, x, Wsc, Wl1, t_sc, t_l1, stats, 0, blk - 256, threadIdx.x);
}

// k4p: blocks [0,512) = FC2 GEMM tiles; blocks [512,768) = P1 g=1 (t_sc hi).
__global__ __launch_bounds__(256) void k4p_w(
    const float* __restrict__ A, const float* __restrict__ Bm,
    float* __restrict__ C,
    const float* __restrict__ x, const float* __restrict__ Wsc,
    const float* __restrict__ Wl1, float* __restrict__ t_sc,
    float* __restrict__ t_l1, float* __restrict__ stats)
{
    __shared__ SharedU su;
    int blk = blockIdx.x;
    if (blk < 512) gemm_phase<512, 1>(su, A, Bm, C, 1024, blk & 31, blk >> 5, threadIdx.x);
    else           phase1(su, x, Wsc, Wl1, t_sc, t_l1, stats, 1, blk - 512, threadIdx.x);
}

__global__ __launch_bounds__(256) void k5_w(
    const float* __restrict__ E2, const unsigned int* __restrict__ maskbits,
    const float* __restrict__ y_g, float* __restrict__ att_out,
    float* __restrict__ stats)
{
    __shared__ SharedU su;
    phase5(su, E2, maskbits, y_g, att_out, stats, blockIdx.x, threadIdx.x);
}

__global__ __launch_bounds__(256) void k6_w(
    const float* __restrict__ att_out, const float* __restrict__ Wdw,
    const float* __restrict__ g2, const float* __restrict__ b2,
    float* __restrict__ stats, float* __restrict__ v_g)
{
    __shared__ SharedU su;
    phase6(su, att_out, Wdw, g2, b2, stats, v_g, blockIdx.x, threadIdx.x);
}

__global__ __launch_bounds__(256) void k7_w(
    const float* __restrict__ v_g, const float* __restrict__ t_sc,
    const float* __restrict__ Wl3, const float* __restrict__ g3,
    const float* __restrict__ b3, const float* __restrict__ gsc,
    const float* __restrict__ bsc, const float* __restrict__ stats,
    float* __restrict__ outp)
{
    __shared__ SharedU su;
    phase7(su, v_g, t_sc, Wl3, g3, b3, gsc, bsc, stats, outp,
           blockIdx.x, blockIdx.y, threadIdx.x);
}

// ---------------------------------------------------------------------------
extern "C" void kernel_launch(void* const* d_in, const int* in_sizes, int n_in,
                              void* d_out, int out_size, void* d_ws, size_t ws_size,
                              hipStream_t stream)
{
    const float* x    = (const float*)d_in[0];
    const float* Wsc  = (const float*)d_in[1];
    const float* gsc  = (const float*)d_in[2];
    const float* bsc  = (const float*)d_in[3];
    const float* Wl1  = (const float*)d_in[4];
    const float* g1   = (const float*)d_in[5];
    const float* b1   = (const float*)d_in[6];
    const float* Wfc1 = (const float*)d_in[7];
    const float* Wfc2 = (const float*)d_in[8];
    const float* g2   = (const float*)d_in[9];
    const float* b2   = (const float*)d_in[10];
    const float* Wdw  = (const float*)d_in[11];
    const float* g3   = (const float*)d_in[12];
    const float* b3   = (const float*)d_in[13];
    const float* Wl3  = (const float*)d_in[14];
    float* outp = (float*)d_out;

    float* ws = (float*)d_ws;
    float* stats = ws;                          // 1024
    float* t_sc  = ws + 1024;                   // 4194304
    float* t_l1  = t_sc + 4194304;              // 2097152 (reused as att_out)
    float* y_g   = t_l1 + 2097152;              // 2097152 (reused as conv out)
    float* E     = y_g + 2097152;               // 524288
    float* H     = E + 524288;                  // 262144
    float* E2    = H + 262144;                  // 524288
    unsigned int* maskb = (unsigned int*)(E2 + 524288);  // 16384 u32

    (void)hipMemsetAsync(stats, 0, 1024 * sizeof(float), stream);

    // critical path: k1a -> k2 -> k3p -> k4p -> k5 -> k6 -> k7
    // t_sc + shortcut-BN stats (only needed by k7) are packed as extra
    // blocks into the two GEMM dispatches (idle-CU overlap, no streams).
    k1a_w<<<256, 256, 0, stream>>>(x, Wsc, Wl1, t_sc, t_l1, stats);
    k2_w<<<512, 256, 0, stream>>>(t_l1, g1, b1, stats, y_g, E, maskb);
    k3p_w<<<512, 256, 0, stream>>>(E, Wfc1, H, x, Wsc, Wl1, t_sc, t_l1, stats);
    k4p_w<<<768, 256, 0, stream>>>(H, Wfc2, E2, x, Wsc, Wl1, t_sc, t_l1, stats);
    k5_w<<<512, 256, 0, stream>>>(E2, maskb, y_g, t_l1, stats);
    k6_w<<<256, 256, 0, stream>>>(t_l1, Wdw, g2, b2, stats, y_g);
    k7_w<<<dim3(2, 256), 256, 0, stream>>>(y_g, t_sc, Wl3, g3, b3, gsc, bsc, stats, outp);
}

// Round 7
// 213.756 us; speedup vs baseline: 2.0767x; 1.1992x over previous
//
#include <hip/hip_runtime.h>
#include <math.h>

// B=8, N=32, M=64, D=128, OUT=128, K=3, P=N*N=1024, r=512
#define EPS 1e-5f

// stats layout (floats) in ws[0..1023]:
//  [0..127]   sum_sc   [128..255] sq_sc
//  [256..319] sum1     [320..383] sq1
//  [384..447] sum2     [448..511] sq2
//  [512..543] sum3     [544..575] sq3

__device__ __forceinline__ void fma4(float4& a, float s, const float4& v) {
    a.x += s * v.x; a.y += s * v.y; a.z += s * v.z; a.w += s * v.w;
}

// ---------------------------------------------------------------------------
// K1: t_sc[b,o,n,d] = sum_m W_sc[o,m] x[b,n,m,d]; t_l1 likewise for W_l1.
// grid (3, 256). Register tile 4ch x 8d per lane; weights transposed in LDS.
__global__ __launch_bounds__(256) void k1_w(
    const float* __restrict__ x, const float* __restrict__ Wsc,
    const float* __restrict__ Wl1, float* __restrict__ t_sc,
    float* __restrict__ t_l1, float* __restrict__ stats)
{
    int g  = blockIdx.x;       // 0..2
    int bn = blockIdx.y;       // 0..255
    int b = bn >> 5, n = bn & 31;
    __shared__ __align__(16) float s_x[64 * 128];
    __shared__ __align__(16) float s_wT[64 * 68];
    int t = threadIdx.x;

    const float4* xg = (const float4*)(x + (size_t)bn * 8192);
    for (int i = t; i < 2048; i += 256) ((float4*)s_x)[i] = xg[i];

    const float* wbase = (g < 2) ? (Wsc + (size_t)g * 64 * 64) : Wl1;
    for (int i = t; i < 1024; i += 256) {
        int m = i >> 4, rq = (i & 15) * 4;
        float4 wv;
        wv.x = wbase[(size_t)(rq + 0) * 64 + m];
        wv.y = wbase[(size_t)(rq + 1) * 64 + m];
        wv.z = wbase[(size_t)(rq + 2) * 64 + m];
        wv.w = wbase[(size_t)(rq + 3) * 64 + m];
        *(float4*)(s_wT + m * 68 + rq) = wv;
    }
    __syncthreads();

    int wv = t >> 6, lane = t & 63;
    int dl = lane & 15, g4 = lane >> 4;
    int d0 = dl * 8;
    int c0 = wv * 16 + g4 * 4;

    float4 acc[4][2];
#pragma unroll
    for (int i = 0; i < 4; i++) { acc[i][0] = make_float4(0,0,0,0); acc[i][1] = make_float4(0,0,0,0); }

    for (int m = 0; m < 64; m += 2) {
        float4 x00 = *(const float4*)(s_x + m * 128 + d0);
        float4 x01 = *(const float4*)(s_x + m * 128 + d0 + 4);
        float4 x10 = *(const float4*)(s_x + (m + 1) * 128 + d0);
        float4 x11 = *(const float4*)(s_x + (m + 1) * 128 + d0 + 4);
        float4 w0 = *(const float4*)(s_wT + m * 68 + c0);
        float4 w1 = *(const float4*)(s_wT + (m + 1) * 68 + c0);
        fma4(acc[0][0], w0.x, x00); fma4(acc[0][1], w0.x, x01);
        fma4(acc[1][0], w0.y, x00); fma4(acc[1][1], w0.y, x01);
        fma4(acc[2][0], w0.z, x00); fma4(acc[2][1], w0.z, x01);
        fma4(acc[3][0], w0.w, x00); fma4(acc[3][1], w0.w, x01);
        fma4(acc[0][0], w1.x, x10); fma4(acc[0][1], w1.x, x11);
        fma4(acc[1][0], w1.y, x10); fma4(acc[1][1], w1.y, x11);
        fma4(acc[2][0], w1.z, x10); fma4(acc[2][1], w1.z, x11);
        fma4(acc[3][0], w1.w, x10); fma4(acc[3][1], w1.w, x11);
    }

#pragma unroll
    for (int i = 0; i < 4; i++) {
        int cc = g * 64 + c0 + i;
        float4 v0 = acc[i][0], v1 = acc[i][1];
        float* dst;
        if (cc < 128) dst = t_sc + (((size_t)(b * 128 + cc)) * 32 + n) * 128 + d0;
        else          dst = t_l1 + (((size_t)(b * 64 + (cc - 128))) * 32 + n) * 128 + d0;
        *(float4*)dst = v0;
        *(float4*)(dst + 4) = v1;
        float s = v0.x + v0.y + v0.z + v0.w + v1.x + v1.y + v1.z + v1.w;
        float q = v0.x*v0.x + v0.y*v0.y + v0.z*v0.z + v0.w*v0.w
                + v1.x*v1.x + v1.y*v1.y + v1.z*v1.z + v1.w*v1.w;
#pragma unroll
        for (int off = 8; off > 0; off >>= 1) {
            s += __shfl_down(s, off, 16);
            q += __shfl_down(q, off, 16);
        }
        if (dl == 0) {
            if (cc < 128) {
                atomicAdd(&stats[cc], s);
                atomicAdd(&stats[cc + 128], q);
            } else {
                atomicAdd(&stats[256 + (cc - 128)], s);
                atomicAdd(&stats[320 + (cc - 128)], q);
            }
        }
    }
}

// ---------------------------------------------------------------------------
// K2: per (b,m) split into 2 blocks (h = half of i-rows). Full y + S in each.
// grid 1024.
__global__ __launch_bounds__(256) void k2_w(
    const float* __restrict__ t_l1, const float* __restrict__ g1,
    const float* __restrict__ b1, const float* __restrict__ stats,
    float* __restrict__ y_g, float* __restrict__ E,
    unsigned int* __restrict__ maskbits)
{
    int blk = blockIdx.x;
    int bm = blk >> 1, h = blk & 1;
    int t  = threadIdx.x;
    __shared__ __align__(16) float y_s[32 * 132];
    __shared__ float S_s[32];
    __shared__ unsigned int m_s[16];
    int m = bm & 63;
    float mean = stats[256 + m] * (1.0f / 32768.0f);
    float var  = stats[320 + m] * (1.0f / 32768.0f) - mean * mean;
    float a = g1[m] * rsqrtf(var + EPS);
    float c = b1[m] - a * mean;

    if (t < 16) m_s[t] = 0u;
    const float4* src = (const float4*)(t_l1 + (size_t)bm * 4096);
    for (int i = t; i < 1024; i += 256) {
        float4 v = src[i];
        v.x = a * v.x + c; v.y = a * v.y + c; v.z = a * v.z + c; v.w = a * v.w + c;
        *(float4*)(y_s + (i >> 5) * 132 + (i & 31) * 4) = v;
    }
    __syncthreads();

    {   // row sums (all 32 rows)
        int r = t >> 3, j = t & 7;
        float s = 0.f;
        const float* yr = y_s + r * 132 + j * 16;
#pragma unroll
        for (int dd = 0; dd < 16; dd++) s += yr[dd];
#pragma unroll
        for (int off = 4; off > 0; off >>= 1) s += __shfl_down(s, off, 8);
        if (j == 0) S_s[r] = s;
    }
    __syncthreads();

    int i_loc = t >> 4;            // 0..15
    int i = h * 16 + i_loc;
    int j0 = (t & 15) * 2;         // 2 j's per thread
    float dot0 = 0.f, dot1 = 0.f, eq0 = 0.f, eq1 = 0.f;
    const float* yi  = y_s + i * 132;
    const float* yj0 = y_s + j0 * 132;
    const float* yj1 = y_s + (j0 + 1) * 132;
    for (int dq = 0; dq < 32; dq++) {
        float4 a4 = *(const float4*)(yi + dq * 4);
        float4 b0 = *(const float4*)(yj0 + dq * 4);
        float4 b1v = *(const float4*)(yj1 + dq * 4);
        dot0 += a4.x * b0.x + a4.y * b0.y + a4.z * b0.z + a4.w * b0.w;
        eq0  += (a4.x == b0.x ? b0.x : 0.f) + (a4.y == b0.y ? b0.y : 0.f)
              + (a4.z == b0.z ? b0.z : 0.f) + (a4.w == b0.w ? b0.w : 0.f);
        dot1 += a4.x * b1v.x + a4.y * b1v.y + a4.z * b1v.z + a4.w * b1v.w;
        eq1  += (a4.x == b1v.x ? b1v.x : 0.f) + (a4.y == b1v.y ? b1v.y : 0.f)
              + (a4.z == b1v.z ? b1v.z : 0.f) + (a4.w == b1v.w ? b1v.w : 0.f);
    }
    float Si = S_s[i];
    float Sj0 = S_s[j0], Sj1 = S_s[j0 + 1];
    unsigned int bits = 0u;
    if (dot0 - Si * Sj0 * (1.0f / 128.0f) > 0.f) bits |= (1u << j0);
    if (dot1 - Si * Sj1 * (1.0f / 128.0f) > 0.f) bits |= (1u << (j0 + 1));
    float ev0 = (Si + 2.f * Sj0 - eq0) * (1.0f / 256.0f);
    float ev1 = (Si + 2.f * Sj1 - eq1) * (1.0f / 256.0f);
    atomicOr(&m_s[i_loc], bits);
    *(float2*)(E + (size_t)bm * 1024 + i * 32 + j0) = make_float2(ev0, ev1);
    __syncthreads();
    if (t < 16) maskbits[bm * 32 + h * 16 + t] = m_s[t];

    // store this block's half of y
    float4* yd = (float4*)(y_g + (size_t)bm * 4096);
    for (int idx = t; idx < 512; idx += 256) {
        int row = h * 16 + (idx >> 5), col = (idx & 31) * 4;
        yd[h * 512 + idx] = *(const float4*)(y_s + row * 132 + col);
    }
}

// ---------------------------------------------------------------------------
// K3: FC1 partial GEMM. C_kz[r,c] = sum_{k in kz-half} E[r,k]*Wfc1[c,k], raw.
// grid 512: kz = blk>>8, tile = blk&255 (ct 0..15, rt 0..15). 32x32 tile,
// 4-wave in-block split-K over 512 k's (SLABS=4).
__global__ __launch_bounds__(256) void k3a_w(
    const float* __restrict__ A, const float* __restrict__ Bm,
    float* __restrict__ Cp)
{
    __shared__ __align__(16) float lds[4 * 2304];
    int blk = blockIdx.x;
    int kz = blk >> 8, tile = blk & 255;
    int ct = tile & 15, rt = tile >> 4;
    const float* Ab = A + kz * 512;
    const float* Bb = Bm + kz * 512;
    float* C = Cp + (size_t)kz * 262144;
    int t = threadIdx.x;
    int w = t >> 6, l = t & 63;
    int row0 = rt * 32, col0 = ct * 32;
    float* As = lds + w * 2304;
    float* Bs = As + 1152;
    int rg = l >> 3, cg = l & 7, kq = (l & 7) * 4;
    const int SLABS = 4, KROW = 1024;

    float4 acc[4];
#pragma unroll
    for (int ii = 0; ii < 4; ii++) acc[ii] = make_float4(0,0,0,0);

    float4 av[4], bv[4], av2[4], bv2[4];
    int k0 = w * 32;
#pragma unroll
    for (int rr = 0; rr < 4; rr++) {
        int r = rg + rr * 8;
        av[rr] = *(const float4*)(Ab + (size_t)(row0 + r) * KROW + k0 + kq);
        bv[rr] = *(const float4*)(Bb + (size_t)(col0 + r) * KROW + k0 + kq);
    }
    for (int s = 0; s < SLABS; s++) {
#pragma unroll
        for (int rr = 0; rr < 4; rr++) {
            int r = rg + rr * 8;
            As[(kq + 0) * 36 + r] = av[rr].x; As[(kq + 1) * 36 + r] = av[rr].y;
            As[(kq + 2) * 36 + r] = av[rr].z; As[(kq + 3) * 36 + r] = av[rr].w;
            Bs[(kq + 0) * 36 + r] = bv[rr].x; Bs[(kq + 1) * 36 + r] = bv[rr].y;
            Bs[(kq + 2) * 36 + r] = bv[rr].z; Bs[(kq + 3) * 36 + r] = bv[rr].w;
        }
        if (s + 1 < SLABS) {
            int kn = (4 * (s + 1) + w) * 32;
#pragma unroll
            for (int rr = 0; rr < 4; rr++) {
                int r = rg + rr * 8;
                av2[rr] = *(const float4*)(Ab + (size_t)(row0 + r) * KROW + kn + kq);
                bv2[rr] = *(const float4*)(Bb + (size_t)(col0 + r) * KROW + kn + kq);
            }
        }
#pragma unroll
        for (int k = 0; k < 32; k++) {
            float4 a = *(const float4*)(As + k * 36 + rg * 4);
            float4 b = *(const float4*)(Bs + k * 36 + cg * 4);
            fma4(acc[0], a.x, b); fma4(acc[1], a.y, b);
            fma4(acc[2], a.z, b); fma4(acc[3], a.w, b);
        }
#pragma unroll
        for (int rr = 0; rr < 4; rr++) { av[rr] = av2[rr]; bv[rr] = bv2[rr]; }
    }

    __syncthreads();
    float* red = lds;
#pragma unroll
    for (int ii = 0; ii < 4; ii++)
        *(float4*)(red + w * 1024 + (rg * 4 + ii) * 32 + cg * 4) = acc[ii];
    __syncthreads();

    int r = t >> 3, c4 = (t & 7) * 4;
    float4 s0 = *(const float4*)(red + r * 32 + c4);
    float4 s1 = *(const float4*)(red + 1024 + r * 32 + c4);
    float4 s2 = *(const float4*)(red + 2048 + r * 32 + c4);
    float4 s3 = *(const float4*)(red + 3072 + r * 32 + c4);
    float4 v;
    v.x = s0.x + s1.x + s2.x + s3.x;
    v.y = s0.y + s1.y + s2.y + s3.y;
    v.z = s0.z + s1.z + s2.z + s3.z;
    v.w = s0.w + s1.w + s2.w + s3.w;
    *(float4*)(C + (size_t)(row0 + r) * 512 + col0 + c4) = v;
}

// ---------------------------------------------------------------------------
// K4: FC2 partial GEMM. A-load = relu(H0+H1) fused. Raw partial out.
// grid 1024: kz = blk>>9, tile = blk&511 (ct 0..31, rt 0..15). SLABS=2.
__global__ __launch_bounds__(256) void k4a_w(
    const float* __restrict__ H0, const float* __restrict__ H1,
    const float* __restrict__ Bm, float* __restrict__ Cp)
{
    __shared__ __align__(16) float lds[4 * 2304];
    int blk = blockIdx.x;
    int kz = blk >> 9, tile = blk & 511;
    int ct = tile & 31, rt = tile >> 5;
    const float* H0b = H0 + kz * 256;
    const float* H1b = H1 + kz * 256;
    const float* Bb  = Bm + kz * 256;
    float* C = Cp + (size_t)kz * 524288;
    int t = threadIdx.x;
    int w = t >> 6, l = t & 63;
    int row0 = rt * 32, col0 = ct * 32;
    float* As = lds + w * 2304;
    float* Bs = As + 1152;
    int rg = l >> 3, cg = l & 7, kq = (l & 7) * 4;
    const int SLABS = 2, KROW = 512;

    float4 acc[4];
#pragma unroll
    for (int ii = 0; ii < 4; ii++) acc[ii] = make_float4(0,0,0,0);

    float4 av[4], bv[4], av2[4], bv2[4];
    int k0 = w * 32;
#pragma unroll
    for (int rr = 0; rr < 4; rr++) {
        int r = rg + rr * 8;
        size_t ai = (size_t)(row0 + r) * KROW + k0 + kq;
        float4 h0 = *(const float4*)(H0b + ai);
        float4 h1 = *(const float4*)(H1b + ai);
        av[rr].x = fmaxf(h0.x + h1.x, 0.f); av[rr].y = fmaxf(h0.y + h1.y, 0.f);
        av[rr].z = fmaxf(h0.z + h1.z, 0.f); av[rr].w = fmaxf(h0.w + h1.w, 0.f);
        bv[rr] = *(const float4*)(Bb + (size_t)(col0 + r) * KROW + k0 + kq);
    }
    for (int s = 0; s < SLABS; s++) {
#pragma unroll
        for (int rr = 0; rr < 4; rr++) {
            int r = rg + rr * 8;
            As[(kq + 0) * 36 + r] = av[rr].x; As[(kq + 1) * 36 + r] = av[rr].y;
            As[(kq + 2) * 36 + r] = av[rr].z; As[(kq + 3) * 36 + r] = av[rr].w;
            Bs[(kq + 0) * 36 + r] = bv[rr].x; Bs[(kq + 1) * 36 + r] = bv[rr].y;
            Bs[(kq + 2) * 36 + r] = bv[rr].z; Bs[(kq + 3) * 36 + r] = bv[rr].w;
        }
        if (s + 1 < SLABS) {
            int kn = (4 * (s + 1) + w) * 32;
#pragma unroll
            for (int rr = 0; rr < 4; rr++) {
                int r = rg + rr * 8;
                size_t ai = (size_t)(row0 + r) * KROW + kn + kq;
                float4 h0 = *(const float4*)(H0b + ai);
                float4 h1 = *(const float4*)(H1b + ai);
                av2[rr].x = fmaxf(h0.x + h1.x, 0.f); av2[rr].y = fmaxf(h0.y + h1.y, 0.f);
                av2[rr].z = fmaxf(h0.z + h1.z, 0.f); av2[rr].w = fmaxf(h0.w + h1.w, 0.f);
                bv2[rr] = *(const float4*)(Bb + (size_t)(col0 + r) * KROW + kn + kq);
            }
        }
#pragma unroll
        for (int k = 0; k < 32; k++) {
            float4 a = *(const float4*)(As + k * 36 + rg * 4);
            float4 b = *(const float4*)(Bs + k * 36 + cg * 4);
            fma4(acc[0], a.x, b); fma4(acc[1], a.y, b);
            fma4(acc[2], a.z, b); fma4(acc[3], a.w, b);
        }
#pragma unroll
        for (int rr = 0; rr < 4; rr++) { av[rr] = av2[rr]; bv[rr] = bv2[rr]; }
    }

    __syncthreads();
    float* red = lds;
#pragma unroll
    for (int ii = 0; ii < 4; ii++)
        *(float4*)(red + w * 1024 + (rg * 4 + ii) * 32 + cg * 4) = acc[ii];
    __syncthreads();

    int r = t >> 3, c4 = (t & 7) * 4;
    float4 s0 = *(const float4*)(red + r * 32 + c4);
    float4 s1 = *(const float4*)(red + 1024 + r * 32 + c4);
    float4 s2 = *(const float4*)(red + 2048 + r * 32 + c4);
    float4 s3 = *(const float4*)(red + 3072 + r * 32 + c4);
    float4 v;
    v.x = s0.x + s1.x + s2.x + s3.x;
    v.y = s0.y + s1.y + s2.y + s3.y;
    v.z = s0.z + s1.z + s2.z + s3.z;
    v.w = s0.w + s1.w + s2.w + s3.w;
    *(float4*)(C + (size_t)(row0 + r) * 1024 + col0 + c4) = v;
}

// ---------------------------------------------------------------------------
// K5: per (b,m) split into 2 blocks of 16 i-rows. sigmoid(E2a+E2b) fused.
// grid 1024.
__global__ __launch_bounds__(256) void k5_w(
    const float* __restrict__ E2a, const float* __restrict__ E2b,
    const unsigned int* __restrict__ maskbits, const float* __restrict__ y_g,
    float* __restrict__ att_out, float* __restrict__ stats)
{
    int blk = blockIdx.x;
    int bm = blk >> 1, h = blk & 1;
    int t  = threadIdx.x;
    __shared__ __align__(16) float att_s[16 * 33];
    __shared__ __align__(16) float y_sh[32 * 128];
    __shared__ float redS[4], redQ[4];

    const float4* ysrc = (const float4*)(y_g + (size_t)bm * 4096);
    for (int i = t; i < 1024; i += 256) ((float4*)y_sh)[i] = ysrc[i];

    {
        int r_loc = t >> 4;            // 0..15
        int r = h * 16 + r_loc;
        int j0 = (t & 15) * 2;
        unsigned int mk = maskbits[bm * 32 + r];
        size_t eidx = (size_t)bm * 1024 + r * 32 + j0;
        float2 ea = *(const float2*)(E2a + eidx);
        float2 eb = *(const float2*)(E2b + eidx);
        float s0r = ea.x + eb.x, s1r = ea.y + eb.y;
        float e0 = 1.0f / (1.0f + expf(-s0r));
        float e1 = 1.0f / (1.0f + expf(-s1r));
        float v0 = ((mk >> (j0 + 0)) & 1u) ? e0 : -1e12f;
        float v1 = ((mk >> (j0 + 1)) & 1u) ? e1 : -1e12f;
        float mx = fmaxf(v0, v1);
#pragma unroll
        for (int off = 1; off < 16; off <<= 1) mx = fmaxf(mx, __shfl_xor(mx, off, 16));
        float x0 = __expf(v0 - mx), x1 = __expf(v1 - mx);
        float sm = x0 + x1;
#pragma unroll
        for (int off = 1; off < 16; off <<= 1) sm += __shfl_xor(sm, off, 16);
        float inv = 1.0f / sm;
        att_s[r_loc * 33 + j0 + 0] = x0 * inv;
        att_s[r_loc * 33 + j0 + 1] = x1 * inv;
    }
    __syncthreads();

    int tx = t & 31, ty = t >> 5;
    int dq = tx * 4;
    float ssum = 0.f, sq = 0.f;
#pragma unroll
    for (int ii = 0; ii < 2; ii++) {
        int i_loc = ty * 2 + ii;
        int i = h * 16 + i_loc;
        float4 acc = make_float4(0.f, 0.f, 0.f, 0.f);
        for (int j = 0; j < 32; j++) {
            float aw = att_s[i_loc * 33 + j];
            float4 yv = *(const float4*)(y_sh + j * 128 + dq);
            acc.x += aw * yv.x; acc.y += aw * yv.y;
            acc.z += aw * yv.z; acc.w += aw * yv.w;
        }
        *(float4*)(att_out + (size_t)bm * 4096 + i * 128 + dq) = acc;
        ssum += acc.x + acc.y + acc.z + acc.w;
        sq   += acc.x * acc.x + acc.y * acc.y + acc.z * acc.z + acc.w * acc.w;
    }
#pragma unroll
    for (int off = 32; off > 0; off >>= 1) {
        ssum += __shfl_down(ssum, off, 64);
        sq   += __shfl_down(sq, off, 64);
    }
    int wave = t >> 6, lane = t & 63;
    if (lane == 0) { redS[wave] = ssum; redQ[wave] = sq; }
    __syncthreads();
    if (t == 0) {
        float S = redS[0] + redS[1] + redS[2] + redS[3];
        float Q = redQ[0] + redQ[1] + redQ[2] + redQ[3];
        int m = bm & 63;
        atomicAdd(&stats[384 + m], S);
        atomicAdd(&stats[448 + m], Q);
    }
}

// ---------------------------------------------------------------------------
// K6: per (b,n) split into 2 blocks along d (64-wide halves + 1-col halo).
// grid 512.
__global__ __launch_bounds__(256) void k6_w(
    const float* __restrict__ att_out, const float* __restrict__ Wdw,
    const float* __restrict__ g2, const float* __restrict__ b2,
    float* __restrict__ stats, float* __restrict__ v_g)
{
    int blk = blockIdx.x;
    int bn = blk >> 1, h = blk & 1;
    int b = bn >> 5, n = bn & 31;
    int dbase = h * 64;
    int t = threadIdx.x;
    __shared__ float z_s[66 * 68];     // [m+1][col], col 0 = d-1 .. col 65 = d+64
    __shared__ float a2_s[64], c2_s[64];
    __shared__ float redS[4], redQ[4];

    if (t < 64) {
        float mean = stats[384 + t] * (1.0f / 32768.0f);
        float var  = stats[448 + t] * (1.0f / 32768.0f) - mean * mean;
        float a = g2[t] * rsqrtf(var + EPS);
        a2_s[t] = a; c2_s[t] = b2[t] - a * mean;
    }
    for (int i = t; i < 66 * 68; i += 256) z_s[i] = 0.f;
    __syncthreads();

    // interior: 64 m x 64 d
    for (int i = t; i < 1024; i += 256) {
        int m = i >> 4, c4 = (i & 15) * 4;
        float4 vv = *(const float4*)(att_out + (((size_t)(b * 64 + m)) * 32 + n) * 128 + dbase + c4);
        float a = a2_s[m], c = c2_s[m];
        float* dst = z_s + (m + 1) * 68 + 1 + c4;
        dst[0] = fmaxf(a * vv.x + c, 0.f);
        dst[1] = fmaxf(a * vv.y + c, 0.f);
        dst[2] = fmaxf(a * vv.z + c, 0.f);
        dst[3] = fmaxf(a * vv.w + c, 0.f);
    }
    // halo columns
    if (t < 128) {
        int m = t & 63, side = t >> 6;
        int d = dbase + (side ? 64 : -1);
        if (d >= 0 && d < 128) {
            float val = att_out[(((size_t)(b * 64 + m)) * 32 + n) * 128 + d];
            z_s[(m + 1) * 68 + (side ? 65 : 0)] = fmaxf(a2_s[m] * val + c2_s[m], 0.f);
        }
    }
    float w[9];
#pragma unroll
    for (int i = 0; i < 9; i++) w[i] = Wdw[n * 9 + i];
    __syncthreads();

    int tx = t & 15, ty = t >> 4;      // tx: d-quad (16*4=64 d), ty: 16 row grps
    int d0 = tx * 4;
    float ssum = 0.f, sq = 0.f;
#pragma unroll
    for (int rr = 0; rr < 4; rr++) {
        int hr = ty * 4 + rr;
        float o0 = 0.f, o1 = 0.f, o2 = 0.f, o3 = 0.f;
#pragma unroll
        for (int dh = 0; dh < 3; dh++) {
            const float* zr = z_s + (hr + dh) * 68 + d0;   // col 0 = d-1
#pragma unroll
            for (int dw = 0; dw < 3; dw++) {
                float wv = w[dh * 3 + dw];
                o0 += wv * zr[dw + 0];
                o1 += wv * zr[dw + 1];
                o2 += wv * zr[dw + 2];
                o3 += wv * zr[dw + 3];
            }
        }
        *(float4*)(v_g + ((size_t)bn * 64 + hr) * 128 + dbase + d0) = make_float4(o0, o1, o2, o3);
        ssum += o0 + o1 + o2 + o3;
        sq   += o0 * o0 + o1 * o1 + o2 * o2 + o3 * o3;
    }
#pragma unroll
    for (int off = 32; off > 0; off >>= 1) {
        ssum += __shfl_down(ssum, off, 64);
        sq   += __shfl_down(sq, off, 64);
    }
    int wave = t >> 6, lane = t & 63;
    if (lane == 0) { redS[wave] = ssum; redQ[wave] = sq; }
    __syncthreads();
    if (t == 0) {
        atomicAdd(&stats[512 + n], redS[0] + redS[1] + redS[2] + redS[3]);
        atomicAdd(&stats[544 + n], redQ[0] + redQ[1] + redQ[2] + redQ[3]);
    }
}

// ---------------------------------------------------------------------------
// K7: out[b,n,o,d] = sum_m Wl3[o,m]*relu(bn3(v[b,n,m,d])) + bn_sc(t_sc)
// grid (2, 256).
__global__ __launch_bounds__(256) void k7_w(
    const float* __restrict__ v_g, const float* __restrict__ t_sc,
    const float* __restrict__ Wl3, const float* __restrict__ g3,
    const float* __restrict__ b3, const float* __restrict__ gsc,
    const float* __restrict__ bsc, const float* __restrict__ stats,
    float* __restrict__ outp)
{
    int oh = blockIdx.x;
    int bn = blockIdx.y;
    int b = bn >> 5, n = bn & 31;
    int t = threadIdx.x;
    __shared__ __align__(16) float z_s[64 * 128];
    __shared__ __align__(16) float s_wT[64 * 68];

    float mean3 = stats[512 + n] * (1.0f / 65536.0f);
    float var3  = stats[544 + n] * (1.0f / 65536.0f) - mean3 * mean3;
    float a3 = g3[n] * rsqrtf(var3 + EPS);
    float c3 = b3[n] - a3 * mean3;

    const float4* vsrc = (const float4*)(v_g + (size_t)bn * 8192);
    for (int i = t; i < 2048; i += 256) {
        float4 vv = vsrc[i];
        float4 r;
        r.x = fmaxf(a3 * vv.x + c3, 0.f);
        r.y = fmaxf(a3 * vv.y + c3, 0.f);
        r.z = fmaxf(a3 * vv.z + c3, 0.f);
        r.w = fmaxf(a3 * vv.w + c3, 0.f);
        ((float4*)z_s)[i] = r;
    }
    const float* wbase = Wl3 + (size_t)oh * 64 * 64;
    for (int i = t; i < 1024; i += 256) {
        int m = i >> 4, rq = (i & 15) * 4;
        float4 wv;
        wv.x = wbase[(size_t)(rq + 0) * 64 + m];
        wv.y = wbase[(size_t)(rq + 1) * 64 + m];
        wv.z = wbase[(size_t)(rq + 2) * 64 + m];
        wv.w = wbase[(size_t)(rq + 3) * 64 + m];
        *(float4*)(s_wT + m * 68 + rq) = wv;
    }
    __syncthreads();

    int wv = t >> 6, lane = t & 63;
    int dl = lane & 15, g4 = lane >> 4;
    int d0 = dl * 8;
    int c0 = wv * 16 + g4 * 4;

    float4 acc[4][2];
#pragma unroll
    for (int i = 0; i < 4; i++) { acc[i][0] = make_float4(0,0,0,0); acc[i][1] = make_float4(0,0,0,0); }

    for (int m = 0; m < 64; m += 2) {
        float4 x00 = *(const float4*)(z_s + m * 128 + d0);
        float4 x01 = *(const float4*)(z_s + m * 128 + d0 + 4);
        float4 x10 = *(const float4*)(z_s + (m + 1) * 128 + d0);
        float4 x11 = *(const float4*)(z_s + (m + 1) * 128 + d0 + 4);
        float4 w0 = *(const float4*)(s_wT + m * 68 + c0);
        float4 w1 = *(const float4*)(s_wT + (m + 1) * 68 + c0);
        fma4(acc[0][0], w0.x, x00); fma4(acc[0][1], w0.x, x01);
        fma4(acc[1][0], w0.y, x00); fma4(acc[1][1], w0.y, x01);
        fma4(acc[2][0], w0.z, x00); fma4(acc[2][1], w0.z, x01);
        fma4(acc[3][0], w0.w, x00); fma4(acc[3][1], w0.w, x01);
        fma4(acc[0][0], w1.x, x10); fma4(acc[0][1], w1.x, x11);
        fma4(acc[1][0], w1.y, x10); fma4(acc[1][1], w1.y, x11);
        fma4(acc[2][0], w1.z, x10); fma4(acc[2][1], w1.z, x11);
        fma4(acc[3][0], w1.w, x10); fma4(acc[3][1], w1.w, x11);
    }

#pragma unroll
    for (int i = 0; i < 4; i++) {
        int o = oh * 64 + c0 + i;
        float msc = stats[o] * (1.0f / 32768.0f);
        float vsc = stats[128 + o] * (1.0f / 32768.0f) - msc * msc;
        float asc = gsc[o] * rsqrtf(vsc + EPS);
        float csc = bsc[o] - asc * msc;
        const float* ts = t_sc + (((size_t)(b * 128 + o)) * 32 + n) * 128 + d0;
        float4 t0 = *(const float4*)(ts);
        float4 t1 = *(const float4*)(ts + 4);
        float4 o0 = acc[i][0], o1 = acc[i][1];
        o0.x += asc * t0.x + csc; o0.y += asc * t0.y + csc;
        o0.z += asc * t0.z + csc; o0.w += asc * t0.w + csc;
        o1.x += asc * t1.x + csc; o1.y += asc * t1.y + csc;
        o1.z += asc * t1.z + csc; o1.w += asc * t1.w + csc;
        float* dst = outp + (((size_t)(b * 32 + n)) * 128 + o) * 128 + d0;
        *(float4*)dst = o0;
        *(float4*)(dst + 4) = o1;
    }
}

// ---------------------------------------------------------------------------
extern "C" void kernel_launch(void* const* d_in, const int* in_sizes, int n_in,
                              void* d_out, int out_size, void* d_ws, size_t ws_size,
                              hipStream_t stream)
{
    const float* x    = (const float*)d_in[0];
    const float* Wsc  = (const float*)d_in[1];
    const float* gsc  = (const float*)d_in[2];
    const float* bsc  = (const float*)d_in[3];
    const float* Wl1  = (const float*)d_in[4];
    const float* g1   = (const float*)d_in[5];
    const float* b1   = (const float*)d_in[6];
    const float* Wfc1 = (const float*)d_in[7];
    const float* Wfc2 = (const float*)d_in[8];
    const float* g2   = (const float*)d_in[9];
    const float* b2   = (const float*)d_in[10];
    const float* Wdw  = (const float*)d_in[11];
    const float* g3   = (const float*)d_in[12];
    const float* b3   = (const float*)d_in[13];
    const float* Wl3  = (const float*)d_in[14];
    float* outp = (float*)d_out;

    float* ws = (float*)d_ws;
    float* stats = ws;                          // 1024
    float* t_sc  = ws + 1024;                   // 4194304
    float* t_l1  = t_sc + 4194304;              // 2097152 (reused as att_out)
    float* y_g   = t_l1 + 2097152;              // 2097152 (reused as conv out)
    float* E     = y_g + 2097152;               // 524288
    float* H0    = E + 524288;                  // 262144
    float* H1    = H0 + 262144;                 // 262144
    float* E2a   = H1 + 262144;                 // 524288
    float* E2b   = E2a + 524288;                // 524288
    unsigned int* maskb = (unsigned int*)(E2b + 524288);  // 16384 u32

    (void)hipMemsetAsync(stats, 0, 1024 * sizeof(float), stream);

    k1_w<<<dim3(3, 256), 256, 0, stream>>>(x, Wsc, Wl1, t_sc, t_l1, stats);
    k2_w<<<1024, 256, 0, stream>>>(t_l1, g1, b1, stats, y_g, E, maskb);
    k3a_w<<<512, 256, 0, stream>>>(E, Wfc1, H0);        // H0/H1 partials
    k4a_w<<<1024, 256, 0, stream>>>(H0, H1, Wfc2, E2a); // E2a/E2b partials
    k5_w<<<1024, 256, 0, stream>>>(E2a, E2b, maskb, y_g, t_l1, stats);
    k6_w<<<512, 256, 0, stream>>>(t_l1, Wdw, g2, b2, stats, y_g);
    k7_w<<<dim3(2, 256), 256, 0, stream>>>(y_g, t_sc, Wl3, g3, b3, gsc, bsc, stats, outp);
}